// Round 1
// baseline (269.468 us; speedup 1.0000x reference)
//
#include <hip/hip_runtime.h>
#include <hip/hip_bf16.h>

#define N_TOK 4096
#define DIM   512
#define HID   1024
#define OUTD  512
#define NEXP  8
#define TOPK  2
#define BT    32

typedef __bf16 bf16;
typedef bf16  bf16x8 __attribute__((ext_vector_type(8)));
typedef bf16  bf16x4 __attribute__((ext_vector_type(4)));
typedef float f32x4  __attribute__((ext_vector_type(4)));

__device__ inline f32x4 mfma16(bf16x8 a, bf16x8 b, f32x4 c) {
    return __builtin_amdgcn_mfma_f32_16x16x32_bf16(a, b, c, 0, 0, 0);
}

// ---------------- gating: logits -> softmax -> top2 -> buckets ----------------
__global__ __launch_bounds__(256) void gate_kernel(
    const float* __restrict__ x, const float* __restrict__ Wg,
    const float* __restrict__ bg,
    float* __restrict__ gates_out, float* __restrict__ topi_out,
    int* __restrict__ counts, int* __restrict__ tlist, float* __restrict__ twgt)
{
    int wave = threadIdx.x >> 6;
    int lane = threadIdx.x & 63;
    int n = blockIdx.x * 4 + wave;
    if (n >= N_TOK) return;

    float acc[NEXP];
#pragma unroll
    for (int e = 0; e < NEXP; ++e) acc[e] = 0.f;

    for (int d = lane; d < DIM; d += 64) {
        float xv = x[n * DIM + d];
        const float* wr = Wg + d * NEXP;
#pragma unroll
        for (int e = 0; e < NEXP; ++e) acc[e] += xv * wr[e];
    }
#pragma unroll
    for (int off = 32; off >= 1; off >>= 1) {
#pragma unroll
        for (int e = 0; e < NEXP; ++e) acc[e] += __shfl_xor(acc[e], off, 64);
    }
#pragma unroll
    for (int e = 0; e < NEXP; ++e) acc[e] += bg[e];

    // softmax (all lanes redundantly)
    float m = acc[0];
#pragma unroll
    for (int e = 1; e < NEXP; ++e) m = fmaxf(m, acc[e]);
    float g[NEXP];
    float s = 0.f;
#pragma unroll
    for (int e = 0; e < NEXP; ++e) { g[e] = expf(acc[e] - m); s += g[e]; }
    float inv_s = 1.f / s;
#pragma unroll
    for (int e = 0; e < NEXP; ++e) g[e] *= inv_s;

    if (lane < NEXP) gates_out[n * NEXP + lane] = g[lane];

    if (lane == 0) {
        int m1 = 0;
#pragma unroll
        for (int e = 1; e < NEXP; ++e) if (g[e] > g[m1]) m1 = e;
        int m2 = (m1 == 0) ? 1 : 0;
#pragma unroll
        for (int e = 0; e < NEXP; ++e) if (e != m1 && g[e] > g[m2]) m2 = e;
        float v1 = g[m1], v2 = g[m2];
        float inv = 1.f / (v1 + v2);
        topi_out[n * TOPK + 0] = (float)m1;
        topi_out[n * TOPK + 1] = (float)m2;
        int p1 = atomicAdd(&counts[m1], 1);
        tlist[m1 * N_TOK + p1] = n;  twgt[m1 * N_TOK + p1] = v1 * inv;
        int p2 = atomicAdd(&counts[m2], 1);
        tlist[m2 * N_TOK + p2] = n;  twgt[m2 * N_TOK + p2] = v2 * inv;
    }
}

// ---------------- x f32 -> bf16 ----------------
__global__ __launch_bounds__(256) void cvt_x_kernel(
    const float4* __restrict__ x, bf16x4* __restrict__ xb, int n4)
{
    int i = blockIdx.x * blockDim.x + threadIdx.x;
    if (i < n4) {
        float4 v = x[i];
        bf16x4 o = { (bf16)v.x, (bf16)v.y, (bf16)v.z, (bf16)v.w };
        xb[i] = o;
    }
}

// ---------------- per-expert transpose [R][C] f32 -> [C][R] bf16 ----------------
__global__ __launch_bounds__(256) void transpose_kernel(
    const float* __restrict__ src, bf16* __restrict__ dst, int R, int C)
{
    __shared__ float tile[32][33];
    int e = blockIdx.z;
    const float* s = src + (size_t)e * R * C;
    bf16* d = dst + (size_t)e * R * C;
    int c0 = blockIdx.x * 32, r0 = blockIdx.y * 32;
    int tx = threadIdx.x & 31, ty = threadIdx.x >> 5;
#pragma unroll
    for (int i = 0; i < 4; ++i) {
        int r = ty + i * 8;
        tile[r][tx] = s[(size_t)(r0 + r) * C + c0 + tx];
    }
    __syncthreads();
#pragma unroll
    for (int i = 0; i < 4; ++i) {
        int r = ty + i * 8;
        d[(size_t)(c0 + r) * R + r0 + tx] = (bf16)tile[tx][r];
    }
}

// ---------------- fused MoE: layer1 -> relu -> LDS -> layer2 -> atomic combine ----
__global__ __launch_bounds__(256, 2) void moe_kernel(
    const bf16* __restrict__ xb, const bf16* __restrict__ W1t,
    const bf16* __restrict__ W2t,
    const float* __restrict__ b1, const float* __restrict__ b2,
    const int* __restrict__ counts, const int* __restrict__ tlist,
    const float* __restrict__ twgt, float* __restrict__ out)
{
    int e    = blockIdx.x & 7;
    int tile = blockIdx.x >> 3;
    int cnt  = counts[e];
    int t0   = tile * BT;
    if (t0 >= cnt) return;

    __shared__ bf16  h_lds[BT * HID];   // 64 KB, XOR-swizzled
    __shared__ int   tok_s[BT];
    __shared__ float wgt_s[BT];

    if (threadIdx.x < BT) {
        int idx = t0 + threadIdx.x;
        bool v = idx < cnt;
        tok_s[threadIdx.x] = v ? tlist[e * N_TOK + idx] : -1;
        wgt_s[threadIdx.x] = v ? twgt[e * N_TOK + idx] : 0.f;
    }
    __syncthreads();

    int wv   = threadIdx.x >> 6;
    int lane = threadIdx.x & 63;
    int lr   = lane & 15;          // row / col selector within fragment
    int lk   = (lane >> 4) * 8;    // k-chunk offset

    int ta0 = tok_s[lr];       ta0 = ta0 < 0 ? 0 : ta0;
    int ta1 = tok_s[16 + lr];  ta1 = ta1 < 0 ? 0 : ta1;
    const bf16* xr0 = xb + (size_t)ta0 * DIM;
    const bf16* xr1 = xb + (size_t)ta1 * DIM;

    // ---- layer 1: h[32 x 1024] = relu(X @ W1_e + b1), this wave: cols n0..n0+255
    const bf16* w1e = W1t + (size_t)e * HID * DIM;   // [H][D]
    int n0 = wv * 256;

    f32x4 acc1[16][2];
#pragma unroll
    for (int nf = 0; nf < 16; ++nf)
#pragma unroll
        for (int mf = 0; mf < 2; ++mf) acc1[nf][mf] = (f32x4){0.f, 0.f, 0.f, 0.f};

    for (int ks = 0; ks < 16; ++ks) {
        int k0 = ks * 32;
        bf16x8 a0 = *(const bf16x8*)(xr0 + k0 + lk);
        bf16x8 a1 = *(const bf16x8*)(xr1 + k0 + lk);
#pragma unroll
        for (int nf = 0; nf < 16; ++nf) {
            bf16x8 b = *(const bf16x8*)(w1e + (size_t)(n0 + nf * 16 + lr) * DIM + k0 + lk);
            acc1[nf][0] = mfma16(a0, b, acc1[nf][0]);
            acc1[nf][1] = mfma16(a1, b, acc1[nf][1]);
        }
    }

    // write h to LDS (bias + relu + bf16), swizzled
    const float* b1e = b1 + e * HID;
#pragma unroll
    for (int nf = 0; nf < 16; ++nf) {
        int col = n0 + nf * 16 + lr;
        float bias = b1e[col];
#pragma unroll
        for (int mf = 0; mf < 2; ++mf) {
#pragma unroll
            for (int r = 0; r < 4; ++r) {
                int row = mf * 16 + (lane >> 4) * 4 + r;
                float v = acc1[nf][mf][r] + bias;
                v = fmaxf(v, 0.f);
                unsigned byte = (unsigned)(row * (HID * 2) + col * 2);
                byte ^= (unsigned)((row & 7) << 4);
                *(bf16*)((char*)h_lds + byte) = (bf16)v;
            }
        }
    }
    __syncthreads();

    // ---- layer 2: y[32 x 512] = h @ W2_e, this wave: cols o0..o0+127
    const bf16* w2e = W2t + (size_t)e * OUTD * HID;  // [O][H]
    int o0 = wv * 128;

    f32x4 acc2[8][2];
#pragma unroll
    for (int nf = 0; nf < 8; ++nf)
#pragma unroll
        for (int mf = 0; mf < 2; ++mf) acc2[nf][mf] = (f32x4){0.f, 0.f, 0.f, 0.f};

    for (int ks = 0; ks < 32; ++ks) {
        int k0 = ks * 32;
        unsigned byte0 = (unsigned)(lr * (HID * 2) + (k0 + lk) * 2);
        byte0 ^= (unsigned)((lr & 7) << 4);
        bf16x8 a0 = *(const bf16x8*)((const char*)h_lds + byte0);
        int row1 = 16 + lr;
        unsigned byte1 = (unsigned)(row1 * (HID * 2) + (k0 + lk) * 2);
        byte1 ^= (unsigned)((row1 & 7) << 4);
        bf16x8 a1 = *(const bf16x8*)((const char*)h_lds + byte1);
#pragma unroll
        for (int nf = 0; nf < 8; ++nf) {
            bf16x8 b = *(const bf16x8*)(w2e + (size_t)(o0 + nf * 16 + lr) * HID + k0 + lk);
            acc2[nf][0] = mfma16(a0, b, acc2[nf][0]);
            acc2[nf][1] = mfma16(a1, b, acc2[nf][1]);
        }
    }

    // epilogue: out[tok] += w * (y + b2)
    const float* b2e = b2 + e * OUTD;
#pragma unroll
    for (int nf = 0; nf < 8; ++nf) {
        int col = o0 + nf * 16 + lr;
        float bias = b2e[col];
#pragma unroll
        for (int mf = 0; mf < 2; ++mf) {
#pragma unroll
            for (int r = 0; r < 4; ++r) {
                int row = mf * 16 + (lane >> 4) * 4 + r;
                int tok = tok_s[row];
                if (tok >= 0) {
                    float v = (acc2[nf][mf][r] + bias) * wgt_s[row];
                    atomicAdd(&out[(size_t)tok * OUTD + col], v);
                }
            }
        }
    }
}

extern "C" void kernel_launch(void* const* d_in, const int* in_sizes, int n_in,
                              void* d_out, int out_size, void* d_ws, size_t ws_size,
                              hipStream_t stream)
{
    const float* x  = (const float*)d_in[0];
    const float* W1 = (const float*)d_in[1];
    const float* b1 = (const float*)d_in[2];
    const float* W2 = (const float*)d_in[3];
    const float* b2 = (const float*)d_in[4];
    const float* Wg = (const float*)d_in[5];
    const float* bg = (const float*)d_in[6];

    float* out_f   = (float*)d_out;                      // [N, OUTD]
    float* gates_o = out_f + (size_t)N_TOK * OUTD;       // [N, E]
    float* topi_o  = gates_o + (size_t)N_TOK * NEXP;     // [N, K] (as floats)

    // workspace layout
    char* ws = (char*)d_ws;
    size_t offW1t = 0;                                   // E*H*D bf16 = 8 MB
    size_t offW2t = offW1t + (size_t)NEXP * HID * DIM * 2;
    size_t offXb  = offW2t + (size_t)NEXP * OUTD * HID * 2;
    size_t offCnt = offXb + (size_t)N_TOK * DIM * 2;
    size_t offTl  = offCnt + 256;
    size_t offTw  = offTl + (size_t)NEXP * N_TOK * 4;

    bf16*  W1t   = (bf16*)(ws + offW1t);
    bf16*  W2t   = (bf16*)(ws + offW2t);
    bf16*  xbuf  = (bf16*)(ws + offXb);
    int*   cnts  = (int*)(ws + offCnt);
    int*   tlist = (int*)(ws + offTl);
    float* twgt  = (float*)(ws + offTw);

    hipMemsetAsync(cnts, 0, NEXP * sizeof(int), stream);
    hipMemsetAsync(out_f, 0, (size_t)N_TOK * OUTD * sizeof(float), stream);

    gate_kernel<<<N_TOK / 4, 256, 0, stream>>>(x, Wg, bg, gates_o, topi_o,
                                               cnts, tlist, twgt);

    int n4 = N_TOK * DIM / 4;
    cvt_x_kernel<<<(n4 + 255) / 256, 256, 0, stream>>>((const float4*)x,
                                                       (bf16x4*)xbuf, n4);

    transpose_kernel<<<dim3(HID / 32, DIM / 32, NEXP), 256, 0, stream>>>(
        W1, W1t, DIM, HID);
    transpose_kernel<<<dim3(OUTD / 32, HID / 32, NEXP), 256, 0, stream>>>(
        W2, W2t, HID, OUTD);

    moe_kernel<<<NEXP * (N_TOK / BT), 256, 0, stream>>>(
        xbuf, W1t, W2t, b1, b2, cnts, tlist, twgt, out_f);
}

// Round 2
// 187.218 us; speedup vs baseline: 1.4393x; 1.4393x over previous
//
#include <hip/hip_runtime.h>
#include <hip/hip_bf16.h>

#define N_TOK 4096
#define DIM   512
#define HID   1024
#define OUTD  512
#define NEXP  8
#define TOPK  2

#define MT1 72     // max 128-row M-tiles (layer1)
#define MT2 136    // max 64-row M-tiles (layer2)
#define HROWS 9216 // max padded rows

typedef __bf16 bf16;
typedef bf16  bf16x8 __attribute__((ext_vector_type(8)));
typedef bf16  bf16x4 __attribute__((ext_vector_type(4)));
typedef float f32x4  __attribute__((ext_vector_type(4)));

__device__ inline f32x4 mfma16(bf16x8 a, bf16x8 b, f32x4 c) {
    return __builtin_amdgcn_mfma_f32_16x16x32_bf16(a, b, c, 0, 0, 0);
}

__device__ inline void gload16(const bf16* g, char* l) {
    __builtin_amdgcn_global_load_lds(
        (const __attribute__((address_space(1))) void*)g,
        (__attribute__((address_space(3))) void*)l, 16, 0, 0);
}

// ------------- gating + x->bf16 convert -------------
__global__ __launch_bounds__(256) void gate_kernel(
    const float* __restrict__ x, const float* __restrict__ Wg,
    const float* __restrict__ bg, bf16* __restrict__ xb,
    float* __restrict__ gates_out, float* __restrict__ topi_out,
    int* __restrict__ counts, int* __restrict__ tlist, float* __restrict__ twgt)
{
    int wave = threadIdx.x >> 6;
    int lane = threadIdx.x & 63;
    int n = blockIdx.x * 4 + wave;

    const float4* x4 = (const float4*)(x + (size_t)n * DIM);
    float4 v0 = x4[lane];
    float4 v1 = x4[lane + 64];

    // fused convert to bf16
    bf16x4 o0 = { (bf16)v0.x, (bf16)v0.y, (bf16)v0.z, (bf16)v0.w };
    bf16x4 o1 = { (bf16)v1.x, (bf16)v1.y, (bf16)v1.z, (bf16)v1.w };
    bf16x4* xb4 = (bf16x4*)(xb + (size_t)n * DIM);
    xb4[lane]      = o0;
    xb4[lane + 64] = o1;

    float acc[NEXP];
#pragma unroll
    for (int e = 0; e < NEXP; ++e) acc[e] = 0.f;

    float xs[8] = { v0.x, v0.y, v0.z, v0.w, v1.x, v1.y, v1.z, v1.w };
    int d0 = lane * 4, d1 = (lane + 64) * 4;
#pragma unroll
    for (int j = 0; j < 4; ++j) {
        const float* wr = Wg + (size_t)(d0 + j) * NEXP;
#pragma unroll
        for (int e = 0; e < NEXP; ++e) acc[e] += xs[j] * wr[e];
    }
#pragma unroll
    for (int j = 0; j < 4; ++j) {
        const float* wr = Wg + (size_t)(d1 + j) * NEXP;
#pragma unroll
        for (int e = 0; e < NEXP; ++e) acc[e] += xs[4 + j] * wr[e];
    }
#pragma unroll
    for (int off = 32; off >= 1; off >>= 1) {
#pragma unroll
        for (int e = 0; e < NEXP; ++e) acc[e] += __shfl_xor(acc[e], off, 64);
    }
#pragma unroll
    for (int e = 0; e < NEXP; ++e) acc[e] += bg[e];

    float m = acc[0];
#pragma unroll
    for (int e = 1; e < NEXP; ++e) m = fmaxf(m, acc[e]);
    float g[NEXP];
    float s = 0.f;
#pragma unroll
    for (int e = 0; e < NEXP; ++e) { g[e] = expf(acc[e] - m); s += g[e]; }
    float inv_s = 1.f / s;
#pragma unroll
    for (int e = 0; e < NEXP; ++e) g[e] *= inv_s;

    if (lane < NEXP) gates_out[n * NEXP + lane] = g[lane];

    if (lane == 0) {
        int m1 = 0;
#pragma unroll
        for (int e = 1; e < NEXP; ++e) if (g[e] > g[m1]) m1 = e;
        int m2 = (m1 == 0) ? 1 : 0;
#pragma unroll
        for (int e = 0; e < NEXP; ++e) if (e != m1 && g[e] > g[m2]) m2 = e;
        float v1g = g[m1], v2g = g[m2];
        float inv = 1.f / (v1g + v2g);
        topi_out[n * TOPK + 0] = (float)m1;
        topi_out[n * TOPK + 1] = (float)m2;
        int p1 = atomicAdd(&counts[m1], 1);
        tlist[m1 * N_TOK + p1] = n;  twgt[m1 * N_TOK + p1] = v1g * inv;
        int p2 = atomicAdd(&counts[m2], 1);
        tlist[m2 * N_TOK + p2] = n;  twgt[m2 * N_TOK + p2] = v2g * inv;
    }
}

// ------------- per-expert transpose [R][C] f32 -> [C][R] bf16 -------------
__global__ __launch_bounds__(256) void transpose_kernel(
    const float* __restrict__ src, bf16* __restrict__ dst, int R, int C)
{
    __shared__ float tile[32][33];
    int e = blockIdx.z;
    const float* s = src + (size_t)e * R * C;
    bf16* d = dst + (size_t)e * R * C;
    int c0 = blockIdx.x * 32, r0 = blockIdx.y * 32;
    int tx = threadIdx.x & 31, ty = threadIdx.x >> 5;
#pragma unroll
    for (int i = 0; i < 4; ++i) {
        int r = ty + i * 8;
        tile[r][tx] = s[(size_t)(r0 + r) * C + c0 + tx];
    }
    __syncthreads();
#pragma unroll
    for (int i = 0; i < 4; ++i) {
        int r = ty + i * 8;
        d[(size_t)(c0 + r) * R + r0 + tx] = (bf16)tile[tx][r];
    }
}

// ------------- tile scheduler (1 block) -------------
__global__ void sched_kernel(const int* __restrict__ counts, int* __restrict__ meta)
{
    if (threadIdx.x != 0) return;
    int* hdr = meta;
    int* s1 = meta + 2;            // 3*MT1 ints: e, row_base, list_idx
    int* s2 = meta + 2 + 3 * MT1;  // 3*MT2 ints
    int base = 0, t1 = 0, t2 = 0;
    for (int e = 0; e < NEXP; ++e) {
        int c = counts[e];
        int n1 = (c + 127) >> 7;
        for (int lt = 0; lt < n1; ++lt) {
            s1[t1 * 3] = e; s1[t1 * 3 + 1] = base + lt * 128; s1[t1 * 3 + 2] = lt * 128; ++t1;
        }
        int n2 = (c + 63) >> 6;
        for (int lt = 0; lt < n2; ++lt) {
            s2[t2 * 3] = e; s2[t2 * 3 + 1] = base + lt * 64; s2[t2 * 3 + 2] = lt * 64; ++t2;
        }
        base += n1 << 7;
    }
    hdr[0] = t1; hdr[1] = t2;
}

// ------------- layer1: h = relu(X_gather @ W1_e + b1), tile 128x128, K=512 -------------
__global__ __launch_bounds__(256, 2) void l1_kernel(
    const bf16* __restrict__ xb, const bf16* __restrict__ W1t,
    const float* __restrict__ b1, const int* __restrict__ counts,
    const int* __restrict__ tlist, const int* __restrict__ meta,
    bf16* __restrict__ h)
{
    int mt = blockIdx.x >> 3, nt = blockIdx.x & 7;
    if (mt >= meta[0]) return;
    const int* s1 = meta + 2 + mt * 3;
    int e = s1[0], rb = s1[1], i0 = s1[2];
    int cnt = counts[e];

    __shared__ __align__(16) char lds[32768];  // 2 bufs x (A 8KB + B 8KB)

    int tid = threadIdx.x, w = tid >> 6, l = tid & 63;
    // staging chunks (16B each): A has 512, B has 512; 2 per thread each
    int c0 = w * 128 + l, c1 = c0 + 64;
    int rA0 = c0 >> 2, kA0 = c0 & 3;
    int rA1 = c1 >> 2, kA1 = c1 & 3;
    int iA0 = i0 + rA0, iA1 = i0 + rA1;
    int tok0 = iA0 < cnt ? tlist[e * N_TOK + iA0] : 0;
    int tok1 = iA1 < cnt ? tlist[e * N_TOK + iA1] : 0;
    const bf16* sA0 = xb + (size_t)tok0 * DIM + kA0 * 8;
    const bf16* sA1 = xb + (size_t)tok1 * DIM + kA1 * 8;
    int n0 = nt * 128;
    const bf16* w1e = W1t + (size_t)e * HID * DIM;
    const bf16* sB0 = w1e + (size_t)(n0 + rA0) * DIM + kA0 * 8;
    const bf16* sB1 = w1e + (size_t)(n0 + rA1) * DIM + kA1 * 8;
    int oA0 = c0 * 16, oA1 = c1 * 16;

    f32x4 acc[4][4];
#pragma unroll
    for (int mf = 0; mf < 4; ++mf)
#pragma unroll
        for (int nf = 0; nf < 4; ++nf) acc[mf][nf] = (f32x4){0.f, 0.f, 0.f, 0.f};

    int wm = w >> 1, wn = w & 1;
    int lr = l & 15, kb = (l >> 4) * 16;

    // prologue: stage tile 0 into buf0
    {
        char* A = lds;       char* B = lds + 8192;
        gload16(sA0, A + oA0); gload16(sA1, A + oA1);
        gload16(sB0, B + oA0); gload16(sB1, B + oA1);
    }

    for (int ks = 0; ks < 16; ++ks) {
        __syncthreads();   // drains vmcnt: buf[ks&1] ready
        if (ks < 15) {     // prefetch next tile into other buf; lands during MFMA
            char* A = lds + (((ks + 1) & 1) * 16384);
            char* B = A + 8192;
            int kof = (ks + 1) * 32;
            gload16(sA0 + kof, A + oA0); gload16(sA1 + kof, A + oA1);
            gload16(sB0 + kof, B + oA0); gload16(sB1 + kof, B + oA1);
        }
        char* A = lds + ((ks & 1) * 16384);
        char* B = A + 8192;
        bf16x8 af[4], bfr[4];
#pragma unroll
        for (int mf = 0; mf < 4; ++mf)
            af[mf] = *(const bf16x8*)(A + (wm * 64 + mf * 16 + lr) * 64 + kb);
#pragma unroll
        for (int nf = 0; nf < 4; ++nf)
            bfr[nf] = *(const bf16x8*)(B + (wn * 64 + nf * 16 + lr) * 64 + kb);
#pragma unroll
        for (int mf = 0; mf < 4; ++mf)
#pragma unroll
            for (int nf = 0; nf < 4; ++nf)
                acc[mf][nf] = mfma16(af[mf], bfr[nf], acc[mf][nf]);
    }

    // epilogue: bias + relu + bf16 store (padded rows get garbage, never read back)
    const float* b1e = b1 + e * HID;
#pragma unroll
    for (int nf = 0; nf < 4; ++nf) {
        int colg = n0 + wn * 64 + nf * 16 + lr;
        float bias = b1e[colg];
#pragma unroll
        for (int mf = 0; mf < 4; ++mf) {
#pragma unroll
            for (int r = 0; r < 4; ++r) {
                int gr = rb + wm * 64 + mf * 16 + (l >> 4) * 4 + r;
                float v = fmaxf(acc[mf][nf][r] + bias, 0.f);
                h[(size_t)gr * HID + colg] = (bf16)v;
            }
        }
    }
}

// ------------- layer2: out[tok] += w*(h @ W2_e + b2), tile 64x128, K=1024 -------------
__global__ __launch_bounds__(256, 2) void l2_kernel(
    const bf16* __restrict__ h, const bf16* __restrict__ W2t,
    const float* __restrict__ b2, const int* __restrict__ counts,
    const int* __restrict__ tlist, const float* __restrict__ twgt,
    const int* __restrict__ meta, float* __restrict__ out)
{
    int mt = blockIdx.x >> 2, nt = blockIdx.x & 3;
    if (mt >= meta[1]) return;
    const int* s2 = meta + 2 + 3 * MT1 + mt * 3;
    int e = s2[0], rb = s2[1], i0 = s2[2];
    int cnt = counts[e];

    __shared__ __align__(16) char lds[24576];  // 2 bufs x (A 4KB + B 8KB)

    int tid = threadIdx.x, w = tid >> 6, l = tid & 63;
    // A: 256 chunks (1/thread), B: 512 chunks (2/thread)
    int cA = w * 64 + l;            int rA = cA >> 2, kA = cA & 3;
    int cB0 = w * 128 + l, cB1 = cB0 + 64;
    int rB0 = cB0 >> 2, kB0 = cB0 & 3;
    int rB1 = cB1 >> 2, kB1 = cB1 & 3;
    int n0 = nt * 128;
    const bf16* sA = h + (size_t)(rb + rA) * HID + kA * 8;
    const bf16* w2e = W2t + (size_t)e * OUTD * HID;
    const bf16* sB0 = w2e + (size_t)(n0 + rB0) * HID + kB0 * 8;
    const bf16* sB1 = w2e + (size_t)(n0 + rB1) * HID + kB1 * 8;
    int oA = cA * 16, oB0 = cB0 * 16, oB1 = cB1 * 16;

    f32x4 acc[2][4];
#pragma unroll
    for (int mf = 0; mf < 2; ++mf)
#pragma unroll
        for (int nf = 0; nf < 4; ++nf) acc[mf][nf] = (f32x4){0.f, 0.f, 0.f, 0.f};

    int wm = w >> 1, wn = w & 1;
    int lr = l & 15, kb = (l >> 4) * 16;

    {
        char* A = lds;       char* B = lds + 4096;
        gload16(sA, A + oA); gload16(sB0, B + oB0); gload16(sB1, B + oB1);
    }

    for (int ks = 0; ks < 32; ++ks) {
        __syncthreads();
        if (ks < 31) {
            char* A = lds + (((ks + 1) & 1) * 12288);
            char* B = A + 4096;
            int kof = (ks + 1) * 32;
            gload16(sA + kof, A + oA);
            gload16(sB0 + kof, B + oB0); gload16(sB1 + kof, B + oB1);
        }
        char* A = lds + ((ks & 1) * 12288);
        char* B = A + 4096;
        bf16x8 af[2], bfr[4];
#pragma unroll
        for (int mf = 0; mf < 2; ++mf)
            af[mf] = *(const bf16x8*)(A + (wm * 32 + mf * 16 + lr) * 64 + kb);
#pragma unroll
        for (int nf = 0; nf < 4; ++nf)
            bfr[nf] = *(const bf16x8*)(B + (wn * 64 + nf * 16 + lr) * 64 + kb);
#pragma unroll
        for (int mf = 0; mf < 2; ++mf)
#pragma unroll
            for (int nf = 0; nf < 4; ++nf)
                acc[mf][nf] = mfma16(af[mf], bfr[nf], acc[mf][nf]);
    }

    const float* b2e = b2 + e * OUTD;
#pragma unroll
    for (int mf = 0; mf < 2; ++mf) {
#pragma unroll
        for (int r = 0; r < 4; ++r) {
            int rloc = wm * 32 + mf * 16 + (l >> 4) * 4 + r;
            int i = i0 + rloc;
            if (i < cnt) {
                int tok = tlist[e * N_TOK + i];
                float wt = twgt[e * N_TOK + i];
#pragma unroll
                for (int nf = 0; nf < 4; ++nf) {
                    int colg = n0 + wn * 64 + nf * 16 + lr;
                    float v = (acc[mf][nf][r] + b2e[colg]) * wt;
                    atomicAdd(out + (size_t)tok * OUTD + colg, v);
                }
            }
        }
    }
}

extern "C" void kernel_launch(void* const* d_in, const int* in_sizes, int n_in,
                              void* d_out, int out_size, void* d_ws, size_t ws_size,
                              hipStream_t stream)
{
    const float* x  = (const float*)d_in[0];
    const float* W1 = (const float*)d_in[1];
    const float* b1 = (const float*)d_in[2];
    const float* W2 = (const float*)d_in[3];
    const float* b2 = (const float*)d_in[4];
    const float* Wg = (const float*)d_in[5];
    const float* bg = (const float*)d_in[6];

    float* out_f   = (float*)d_out;
    float* gates_o = out_f + (size_t)N_TOK * OUTD;
    float* topi_o  = gates_o + (size_t)N_TOK * NEXP;

    char* ws = (char*)d_ws;
    size_t offW1t  = 0;                                           // 8 MB
    size_t offW2t  = offW1t + (size_t)NEXP * HID * DIM * 2;       // 8 MB
    size_t offXb   = offW2t + (size_t)NEXP * OUTD * HID * 2;      // 4 MB
    size_t offH    = offXb + (size_t)N_TOK * DIM * 2;             // 18.9 MB
    size_t offCnt  = offH + (size_t)HROWS * HID * 2;
    size_t offTl   = offCnt + 256;
    size_t offTw   = offTl + (size_t)NEXP * N_TOK * 4;
    size_t offMeta = offTw + (size_t)NEXP * N_TOK * 4;

    bf16*  W1t   = (bf16*)(ws + offW1t);
    bf16*  W2t   = (bf16*)(ws + offW2t);
    bf16*  xbuf  = (bf16*)(ws + offXb);
    bf16*  hbuf  = (bf16*)(ws + offH);
    int*   cnts  = (int*)(ws + offCnt);
    int*   tlist = (int*)(ws + offTl);
    float* twgt  = (float*)(ws + offTw);
    int*   meta  = (int*)(ws + offMeta);

    hipMemsetAsync(cnts, 0, NEXP * sizeof(int), stream);
    hipMemsetAsync(out_f, 0, (size_t)N_TOK * OUTD * sizeof(float), stream);

    gate_kernel<<<N_TOK / 4, 256, 0, stream>>>(x, Wg, bg, xbuf, gates_o, topi_o,
                                               cnts, tlist, twgt);

    transpose_kernel<<<dim3(HID / 32, DIM / 32, NEXP), 256, 0, stream>>>(
        W1, W1t, DIM, HID);
    transpose_kernel<<<dim3(OUTD / 32, HID / 32, NEXP), 256, 0, stream>>>(
        W2, W2t, HID, OUTD);

    sched_kernel<<<1, 64, 0, stream>>>(cnts, meta);

    l1_kernel<<<MT1 * 8, 256, 0, stream>>>(xbuf, W1t, b1, cnts, tlist, meta, hbuf);
    l2_kernel<<<MT2 * 4, 256, 0, stream>>>(hbuf, W2t, b2, cnts, tlist, twgt, meta, out_f);
}

// Round 3
// 115.045 us; speedup vs baseline: 2.3423x; 1.6273x over previous
//
#include <hip/hip_runtime.h>
#include <hip/hip_bf16.h>

#define N_TOK 4096
#define DIM   512
#define HID   1024
#define OUTD  512
#define NEXP  8
#define TOPK  2

#define MT1 72     // max 128-row M-tiles (layer1)
#define MT2 136    // max 64-row M-tiles (layer2)
#define HROWS 9216 // max padded rows

typedef __bf16 bf16;
typedef bf16  bf16x8 __attribute__((ext_vector_type(8)));
typedef bf16  bf16x4 __attribute__((ext_vector_type(4)));
typedef float f32x4  __attribute__((ext_vector_type(4)));

__device__ inline f32x4 mfma16(bf16x8 a, bf16x8 b, f32x4 c) {
    return __builtin_amdgcn_mfma_f32_16x16x32_bf16(a, b, c, 0, 0, 0);
}

__device__ inline void gload16(const bf16* g, char* l) {
    __builtin_amdgcn_global_load_lds(
        (const __attribute__((address_space(1))) void*)g,
        (__attribute__((address_space(3))) void*)l, 16, 0, 0);
}

// ------------- Wg [D][E] -> WgT [E][D] (16 KB, one block) -------------
__global__ __launch_bounds__(256) void wgt_kernel(
    const float* __restrict__ Wg, float* __restrict__ WgT)
{
    for (int i = threadIdx.x; i < DIM * NEXP; i += 256) {
        int d = i >> 3, e = i & 7;
        WgT[e * DIM + d] = Wg[i];
    }
}

// ------------- gating + x->bf16 convert (no global atomics) -------------
__global__ __launch_bounds__(256) void gate_kernel(
    const float* __restrict__ x, const float* __restrict__ WgT,
    const float* __restrict__ bg, bf16* __restrict__ xb,
    float* __restrict__ gates_out, float* __restrict__ topi_out,
    int* __restrict__ pick_e, float* __restrict__ pick_w)
{
    int wave = threadIdx.x >> 6;
    int lane = threadIdx.x & 63;
    int n = blockIdx.x * 4 + wave;

    const float4* x4 = (const float4*)(x + (size_t)n * DIM);
    float4 v0 = x4[lane];
    float4 v1 = x4[lane + 64];

    // fused convert to bf16
    bf16x4 o0 = { (bf16)v0.x, (bf16)v0.y, (bf16)v0.z, (bf16)v0.w };
    bf16x4 o1 = { (bf16)v1.x, (bf16)v1.y, (bf16)v1.z, (bf16)v1.w };
    bf16x4* xb4 = (bf16x4*)(xb + (size_t)n * DIM);
    xb4[lane]      = o0;
    xb4[lane + 64] = o1;

    float acc[NEXP];
#pragma unroll
    for (int e = 0; e < NEXP; ++e) {
        const float4* wr = (const float4*)(WgT + e * DIM);
        float4 w0 = wr[lane];
        float4 w1 = wr[lane + 64];
        acc[e] = v0.x * w0.x + v0.y * w0.y + v0.z * w0.z + v0.w * w0.w
               + v1.x * w1.x + v1.y * w1.y + v1.z * w1.z + v1.w * w1.w;
    }
#pragma unroll
    for (int off = 32; off >= 1; off >>= 1) {
#pragma unroll
        for (int e = 0; e < NEXP; ++e) acc[e] += __shfl_xor(acc[e], off, 64);
    }
#pragma unroll
    for (int e = 0; e < NEXP; ++e) acc[e] += bg[e];

    float m = acc[0];
#pragma unroll
    for (int e = 1; e < NEXP; ++e) m = fmaxf(m, acc[e]);
    float g[NEXP];
    float s = 0.f;
#pragma unroll
    for (int e = 0; e < NEXP; ++e) { g[e] = expf(acc[e] - m); s += g[e]; }
    float inv_s = 1.f / s;
#pragma unroll
    for (int e = 0; e < NEXP; ++e) g[e] *= inv_s;

    if (lane < NEXP) gates_out[n * NEXP + lane] = g[lane];

    if (lane == 0) {
        int m1 = 0;
#pragma unroll
        for (int e = 1; e < NEXP; ++e) if (g[e] > g[m1]) m1 = e;
        int m2 = (m1 == 0) ? 1 : 0;
#pragma unroll
        for (int e = 0; e < NEXP; ++e) if (e != m1 && g[e] > g[m2]) m2 = e;
        float v1g = g[m1], v2g = g[m2];
        float inv = 1.f / (v1g + v2g);
        topi_out[n * TOPK + 0] = (float)m1;
        topi_out[n * TOPK + 1] = (float)m2;
        int2 pe = { m1, m2 };
        float2 pw = { v1g * inv, v2g * inv };
        *(int2*)(pick_e + n * 2) = pe;
        *(float2*)(pick_w + n * 2) = pw;
    }
}

// ------------- bucket: 8 blocks (one per expert), LDS-atomic append -------------
__global__ __launch_bounds__(256) void bucket_kernel(
    const int* __restrict__ pick_e, const float* __restrict__ pick_w,
    int* __restrict__ counts, int* __restrict__ tlist, float* __restrict__ twgt)
{
    __shared__ int cnt;
    if (threadIdx.x == 0) cnt = 0;
    __syncthreads();
    int e = blockIdx.x;
    for (int i = threadIdx.x; i < N_TOK * 2; i += 256) {
        if (pick_e[i] == e) {
            int p = atomicAdd(&cnt, 1);
            tlist[e * N_TOK + p] = i >> 1;
            twgt[e * N_TOK + p] = pick_w[i];
        }
    }
    __syncthreads();
    if (threadIdx.x == 0) counts[e] = cnt;
}

// ------------- per-expert transpose [R][C] f32 -> [C][R] bf16 -------------
__global__ __launch_bounds__(256) void transpose_kernel(
    const float* __restrict__ src, bf16* __restrict__ dst, int R, int C)
{
    __shared__ float tile[32][33];
    int e = blockIdx.z;
    const float* s = src + (size_t)e * R * C;
    bf16* d = dst + (size_t)e * R * C;
    int c0 = blockIdx.x * 32, r0 = blockIdx.y * 32;
    int tx = threadIdx.x & 31, ty = threadIdx.x >> 5;
#pragma unroll
    for (int i = 0; i < 4; ++i) {
        int r = ty + i * 8;
        tile[r][tx] = s[(size_t)(r0 + r) * C + c0 + tx];
    }
    __syncthreads();
#pragma unroll
    for (int i = 0; i < 4; ++i) {
        int r = ty + i * 8;
        d[(size_t)(c0 + r) * R + r0 + tx] = (bf16)tile[tx][r];
    }
}

// ------------- tile scheduler (1 block) -------------
__global__ void sched_kernel(const int* __restrict__ counts, int* __restrict__ meta)
{
    if (threadIdx.x != 0) return;
    int* hdr = meta;
    int* s1 = meta + 2;            // 3*MT1 ints: e, row_base, list_idx
    int* s2 = meta + 2 + 3 * MT1;  // 3*MT2 ints
    int base = 0, t1 = 0, t2 = 0;
    for (int e = 0; e < NEXP; ++e) {
        int c = counts[e];
        int n1 = (c + 127) >> 7;
        for (int lt = 0; lt < n1; ++lt) {
            s1[t1 * 3] = e; s1[t1 * 3 + 1] = base + lt * 128; s1[t1 * 3 + 2] = lt * 128; ++t1;
        }
        int n2 = (c + 63) >> 6;
        for (int lt = 0; lt < n2; ++lt) {
            s2[t2 * 3] = e; s2[t2 * 3 + 1] = base + lt * 64; s2[t2 * 3 + 2] = lt * 64; ++t2;
        }
        base += n1 << 7;
    }
    hdr[0] = t1; hdr[1] = t2;
}

// ------------- layer1: h = relu(X_gather @ W1_e + b1), tile 128x128, K=512 -------------
__global__ __launch_bounds__(256, 2) void l1_kernel(
    const bf16* __restrict__ xb, const bf16* __restrict__ W1t,
    const float* __restrict__ b1, const int* __restrict__ counts,
    const int* __restrict__ tlist, const int* __restrict__ meta,
    bf16* __restrict__ h)
{
    int mt = blockIdx.x >> 3, nt = blockIdx.x & 7;
    if (mt >= meta[0]) return;
    const int* s1 = meta + 2 + mt * 3;
    int e = s1[0], rb = s1[1], i0 = s1[2];
    int cnt = counts[e];

    __shared__ __align__(16) char lds[32768];  // 2 bufs x (A 8KB + B 8KB)

    int tid = threadIdx.x, w = tid >> 6, l = tid & 63;
    int c0 = w * 128 + l, c1 = c0 + 64;
    int rA0 = c0 >> 2, kA0 = c0 & 3;
    int rA1 = c1 >> 2, kA1 = c1 & 3;
    int iA0 = i0 + rA0, iA1 = i0 + rA1;
    int tok0 = iA0 < cnt ? tlist[e * N_TOK + iA0] : 0;
    int tok1 = iA1 < cnt ? tlist[e * N_TOK + iA1] : 0;
    const bf16* sA0 = xb + (size_t)tok0 * DIM + kA0 * 8;
    const bf16* sA1 = xb + (size_t)tok1 * DIM + kA1 * 8;
    int n0 = nt * 128;
    const bf16* w1e = W1t + (size_t)e * HID * DIM;
    const bf16* sB0 = w1e + (size_t)(n0 + rA0) * DIM + kA0 * 8;
    const bf16* sB1 = w1e + (size_t)(n0 + rA1) * DIM + kA1 * 8;
    int oA0 = c0 * 16, oA1 = c1 * 16;

    f32x4 acc[4][4];
#pragma unroll
    for (int mf = 0; mf < 4; ++mf)
#pragma unroll
        for (int nf = 0; nf < 4; ++nf) acc[mf][nf] = (f32x4){0.f, 0.f, 0.f, 0.f};

    int wm = w >> 1, wn = w & 1;
    int lr = l & 15, kb = (l >> 4) * 16;

    {
        char* A = lds;       char* B = lds + 8192;
        gload16(sA0, A + oA0); gload16(sA1, A + oA1);
        gload16(sB0, B + oA0); gload16(sB1, B + oA1);
    }

    for (int ks = 0; ks < 16; ++ks) {
        __syncthreads();
        if (ks < 15) {
            char* A = lds + (((ks + 1) & 1) * 16384);
            char* B = A + 8192;
            int kof = (ks + 1) * 32;
            gload16(sA0 + kof, A + oA0); gload16(sA1 + kof, A + oA1);
            gload16(sB0 + kof, B + oA0); gload16(sB1 + kof, B + oA1);
        }
        char* A = lds + ((ks & 1) * 16384);
        char* B = A + 8192;
        bf16x8 af[4], bfr[4];
#pragma unroll
        for (int mf = 0; mf < 4; ++mf)
            af[mf] = *(const bf16x8*)(A + (wm * 64 + mf * 16 + lr) * 64 + kb);
#pragma unroll
        for (int nf = 0; nf < 4; ++nf)
            bfr[nf] = *(const bf16x8*)(B + (wn * 64 + nf * 16 + lr) * 64 + kb);
#pragma unroll
        for (int mf = 0; mf < 4; ++mf)
#pragma unroll
            for (int nf = 0; nf < 4; ++nf)
                acc[mf][nf] = mfma16(af[mf], bfr[nf], acc[mf][nf]);
    }

    const float* b1e = b1 + e * HID;
#pragma unroll
    for (int nf = 0; nf < 4; ++nf) {
        int colg = n0 + wn * 64 + nf * 16 + lr;
        float bias = b1e[colg];
#pragma unroll
        for (int mf = 0; mf < 4; ++mf) {
#pragma unroll
            for (int r = 0; r < 4; ++r) {
                int gr = rb + wm * 64 + mf * 16 + (l >> 4) * 4 + r;
                float v = fmaxf(acc[mf][nf][r] + bias, 0.f);
                h[(size_t)gr * HID + colg] = (bf16)v;
            }
        }
    }
}

// ------------- layer2: out[tok] += w*(h @ W2_e + b2), tile 64x128, K=1024 -------------
__global__ __launch_bounds__(256, 2) void l2_kernel(
    const bf16* __restrict__ h, const bf16* __restrict__ W2t,
    const float* __restrict__ b2, const int* __restrict__ counts,
    const int* __restrict__ tlist, const float* __restrict__ twgt,
    const int* __restrict__ meta, float* __restrict__ out)
{
    int mt = blockIdx.x >> 2, nt = blockIdx.x & 3;
    if (mt >= meta[1]) return;
    const int* s2 = meta + 2 + 3 * MT1 + mt * 3;
    int e = s2[0], rb = s2[1], i0 = s2[2];
    int cnt = counts[e];

    __shared__ __align__(16) char lds[24576];

    int tid = threadIdx.x, w = tid >> 6, l = tid & 63;
    int cA = w * 64 + l;            int rA = cA >> 2, kA = cA & 3;
    int cB0 = w * 128 + l, cB1 = cB0 + 64;
    int rB0 = cB0 >> 2, kB0 = cB0 & 3;
    int rB1 = cB1 >> 2, kB1 = cB1 & 3;
    int n0 = nt * 128;
    const bf16* sA = h + (size_t)(rb + rA) * HID + kA * 8;
    const bf16* w2e = W2t + (size_t)e * OUTD * HID;
    const bf16* sB0 = w2e + (size_t)(n0 + rB0) * HID + kB0 * 8;
    const bf16* sB1 = w2e + (size_t)(n0 + rB1) * HID + kB1 * 8;
    int oA = cA * 16, oB0 = cB0 * 16, oB1 = cB1 * 16;

    f32x4 acc[2][4];
#pragma unroll
    for (int mf = 0; mf < 2; ++mf)
#pragma unroll
        for (int nf = 0; nf < 4; ++nf) acc[mf][nf] = (f32x4){0.f, 0.f, 0.f, 0.f};

    int wm = w >> 1, wn = w & 1;
    int lr = l & 15, kb = (l >> 4) * 16;

    {
        char* A = lds;       char* B = lds + 4096;
        gload16(sA, A + oA); gload16(sB0, B + oB0); gload16(sB1, B + oB1);
    }

    for (int ks = 0; ks < 32; ++ks) {
        __syncthreads();
        if (ks < 31) {
            char* A = lds + (((ks + 1) & 1) * 12288);
            char* B = A + 4096;
            int kof = (ks + 1) * 32;
            gload16(sA + kof, A + oA);
            gload16(sB0 + kof, B + oB0); gload16(sB1 + kof, B + oB1);
        }
        char* A = lds + ((ks & 1) * 12288);
        char* B = A + 4096;
        bf16x8 af[2], bfr[4];
#pragma unroll
        for (int mf = 0; mf < 2; ++mf)
            af[mf] = *(const bf16x8*)(A + (wm * 32 + mf * 16 + lr) * 64 + kb);
#pragma unroll
        for (int nf = 0; nf < 4; ++nf)
            bfr[nf] = *(const bf16x8*)(B + (wn * 64 + nf * 16 + lr) * 64 + kb);
#pragma unroll
        for (int mf = 0; mf < 2; ++mf)
#pragma unroll
            for (int nf = 0; nf < 4; ++nf)
                acc[mf][nf] = mfma16(af[mf], bfr[nf], acc[mf][nf]);
    }

    const float* b2e = b2 + e * OUTD;
#pragma unroll
    for (int mf = 0; mf < 2; ++mf) {
#pragma unroll
        for (int r = 0; r < 4; ++r) {
            int rloc = wm * 32 + mf * 16 + (l >> 4) * 4 + r;
            int i = i0 + rloc;
            if (i < cnt) {
                int tok = tlist[e * N_TOK + i];
                float wt = twgt[e * N_TOK + i];
#pragma unroll
                for (int nf = 0; nf < 4; ++nf) {
                    int colg = n0 + wn * 64 + nf * 16 + lr;
                    float v = (acc[mf][nf][r] + b2e[colg]) * wt;
                    atomicAdd(out + (size_t)tok * OUTD + colg, v);
                }
            }
        }
    }
}

extern "C" void kernel_launch(void* const* d_in, const int* in_sizes, int n_in,
                              void* d_out, int out_size, void* d_ws, size_t ws_size,
                              hipStream_t stream)
{
    const float* x  = (const float*)d_in[0];
    const float* W1 = (const float*)d_in[1];
    const float* b1 = (const float*)d_in[2];
    const float* W2 = (const float*)d_in[3];
    const float* b2 = (const float*)d_in[4];
    const float* Wg = (const float*)d_in[5];
    const float* bg = (const float*)d_in[6];

    float* out_f   = (float*)d_out;
    float* gates_o = out_f + (size_t)N_TOK * OUTD;
    float* topi_o  = gates_o + (size_t)N_TOK * NEXP;

    char* ws = (char*)d_ws;
    size_t offW1t  = 0;                                           // 8 MB
    size_t offW2t  = offW1t + (size_t)NEXP * HID * DIM * 2;       // 8 MB
    size_t offXb   = offW2t + (size_t)NEXP * OUTD * HID * 2;      // 4 MB
    size_t offH    = offXb + (size_t)N_TOK * DIM * 2;             // 18.9 MB
    size_t offCnt  = offH + (size_t)HROWS * HID * 2;
    size_t offTl   = offCnt + 256;
    size_t offTw   = offTl + (size_t)NEXP * N_TOK * 4;
    size_t offMeta = offTw + (size_t)NEXP * N_TOK * 4;
    size_t offPkE  = offMeta + 4096;
    size_t offPkW  = offPkE + (size_t)N_TOK * 2 * 4;
    size_t offWgT  = offPkW + (size_t)N_TOK * 2 * 4;

    bf16*  W1t   = (bf16*)(ws + offW1t);
    bf16*  W2t   = (bf16*)(ws + offW2t);
    bf16*  xbuf  = (bf16*)(ws + offXb);
    bf16*  hbuf  = (bf16*)(ws + offH);
    int*   cnts  = (int*)(ws + offCnt);
    int*   tlist = (int*)(ws + offTl);
    float* twgt  = (float*)(ws + offTw);
    int*   meta  = (int*)(ws + offMeta);
    int*   pick_e = (int*)(ws + offPkE);
    float* pick_w = (float*)(ws + offPkW);
    float* WgT   = (float*)(ws + offWgT);

    hipMemsetAsync(out_f, 0, (size_t)N_TOK * OUTD * sizeof(float), stream);

    wgt_kernel<<<1, 256, 0, stream>>>(Wg, WgT);

    gate_kernel<<<N_TOK / 4, 256, 0, stream>>>(x, WgT, bg, xbuf, gates_o, topi_o,
                                               pick_e, pick_w);

    transpose_kernel<<<dim3(HID / 32, DIM / 32, NEXP), 256, 0, stream>>>(
        W1, W1t, DIM, HID);
    transpose_kernel<<<dim3(OUTD / 32, HID / 32, NEXP), 256, 0, stream>>>(
        W2, W2t, HID, OUTD);

    bucket_kernel<<<NEXP, 256, 0, stream>>>(pick_e, pick_w, cnts, tlist, twgt);

    sched_kernel<<<1, 64, 0, stream>>>(cnts, meta);

    l1_kernel<<<MT1 * 8, 256, 0, stream>>>(xbuf, W1t, b1, cnts, tlist, meta, hbuf);
    l2_kernel<<<MT2 * 4, 256, 0, stream>>>(hbuf, W2t, b2, cnts, tlist, twgt, meta, out_f);
}

// Round 4
// 97.229 us; speedup vs baseline: 2.7715x; 1.1832x over previous
//
#include <hip/hip_runtime.h>
#include <hip/hip_bf16.h>

#define N_TOK 4096
#define DIM   512
#define HID   1024
#define OUTD  512
#define NEXP  8
#define TOPK  2

#define MT1 72     // max 128-row M-tiles (layer1)
#define MT2 136    // max 64-row M-tiles (layer2)
#define HROWS 9216 // max padded rows

typedef __bf16 bf16;
typedef bf16  bf16x8 __attribute__((ext_vector_type(8)));
typedef bf16  bf16x4 __attribute__((ext_vector_type(4)));
typedef float f32x4  __attribute__((ext_vector_type(4)));

__device__ inline f32x4 mfma16(bf16x8 a, bf16x8 b, f32x4 c) {
    return __builtin_amdgcn_mfma_f32_16x16x32_bf16(a, b, c, 0, 0, 0);
}

__device__ inline void gload16(const bf16* g, char* l) {
    __builtin_amdgcn_global_load_lds(
        (const __attribute__((address_space(1))) void*)g,
        (__attribute__((address_space(3))) void*)l, 16, 0, 0);
}

// ------------- Wg [D][E] -> WgT [E][D] (16 KB, one block) -------------
__global__ __launch_bounds__(256) void wgt_kernel(
    const float* __restrict__ Wg, float* __restrict__ WgT)
{
    for (int i = threadIdx.x; i < DIM * NEXP; i += 256) {
        int d = i >> 3, e = i & 7;
        WgT[e * DIM + d] = Wg[i];
    }
}

// ------------- gating + x->bf16 convert (no global atomics) -------------
__global__ __launch_bounds__(256) void gate_kernel(
    const float* __restrict__ x, const float* __restrict__ WgT,
    const float* __restrict__ bg, bf16* __restrict__ xb,
    float* __restrict__ gates_out, float* __restrict__ topi_out,
    int* __restrict__ pick_e, float* __restrict__ pick_w)
{
    int wave = threadIdx.x >> 6;
    int lane = threadIdx.x & 63;
    int n = blockIdx.x * 4 + wave;

    const float4* x4 = (const float4*)(x + (size_t)n * DIM);
    float4 v0 = x4[lane];
    float4 v1 = x4[lane + 64];

    bf16x4 o0 = { (bf16)v0.x, (bf16)v0.y, (bf16)v0.z, (bf16)v0.w };
    bf16x4 o1 = { (bf16)v1.x, (bf16)v1.y, (bf16)v1.z, (bf16)v1.w };
    bf16x4* xb4 = (bf16x4*)(xb + (size_t)n * DIM);
    xb4[lane]      = o0;
    xb4[lane + 64] = o1;

    float acc[NEXP];
#pragma unroll
    for (int e = 0; e < NEXP; ++e) {
        const float4* wr = (const float4*)(WgT + e * DIM);
        float4 w0 = wr[lane];
        float4 w1 = wr[lane + 64];
        acc[e] = v0.x * w0.x + v0.y * w0.y + v0.z * w0.z + v0.w * w0.w
               + v1.x * w1.x + v1.y * w1.y + v1.z * w1.z + v1.w * w1.w;
    }
#pragma unroll
    for (int off = 32; off >= 1; off >>= 1) {
#pragma unroll
        for (int e = 0; e < NEXP; ++e) acc[e] += __shfl_xor(acc[e], off, 64);
    }
#pragma unroll
    for (int e = 0; e < NEXP; ++e) acc[e] += bg[e];

    float m = acc[0];
#pragma unroll
    for (int e = 1; e < NEXP; ++e) m = fmaxf(m, acc[e]);
    float g[NEXP];
    float s = 0.f;
#pragma unroll
    for (int e = 0; e < NEXP; ++e) { g[e] = expf(acc[e] - m); s += g[e]; }
    float inv_s = 1.f / s;
#pragma unroll
    for (int e = 0; e < NEXP; ++e) g[e] *= inv_s;

    if (lane < NEXP) gates_out[n * NEXP + lane] = g[lane];

    if (lane == 0) {
        int m1 = 0;
#pragma unroll
        for (int e = 1; e < NEXP; ++e) if (g[e] > g[m1]) m1 = e;
        int m2 = (m1 == 0) ? 1 : 0;
#pragma unroll
        for (int e = 0; e < NEXP; ++e) if (e != m1 && g[e] > g[m2]) m2 = e;
        float v1g = g[m1], v2g = g[m2];
        float inv = 1.f / (v1g + v2g);
        topi_out[n * TOPK + 0] = (float)m1;
        topi_out[n * TOPK + 1] = (float)m2;
        int2 pe = { m1, m2 };
        float2 pw = { v1g * inv, v2g * inv };
        *(int2*)(pick_e + n * 2) = pe;
        *(float2*)(pick_w + n * 2) = pw;
    }
}

// ------------- bucket: 8 blocks (one per expert); stores pick-index -------------
__global__ __launch_bounds__(256) void bucket_kernel(
    const int* __restrict__ pick_e,
    int* __restrict__ counts, int* __restrict__ tlist)
{
    __shared__ int cnt;
    if (threadIdx.x == 0) cnt = 0;
    __syncthreads();
    int e = blockIdx.x;
    for (int i = threadIdx.x; i < N_TOK * 2; i += 256) {
        if (pick_e[i] == e) {
            int p = atomicAdd(&cnt, 1);
            tlist[e * N_TOK + p] = i;   // pick index: token*2 + slot
        }
    }
    __syncthreads();
    if (threadIdx.x == 0) counts[e] = cnt;
}

// ------------- per-expert transpose [R][C] f32 -> [C][R] bf16 -------------
__global__ __launch_bounds__(256) void transpose_kernel(
    const float* __restrict__ src, bf16* __restrict__ dst, int R, int C)
{
    __shared__ float tile[32][33];
    int e = blockIdx.z;
    const float* s = src + (size_t)e * R * C;
    bf16* d = dst + (size_t)e * R * C;
    int c0 = blockIdx.x * 32, r0 = blockIdx.y * 32;
    int tx = threadIdx.x & 31, ty = threadIdx.x >> 5;
#pragma unroll
    for (int i = 0; i < 4; ++i) {
        int r = ty + i * 8;
        tile[r][tx] = s[(size_t)(r0 + r) * C + c0 + tx];
    }
    __syncthreads();
#pragma unroll
    for (int i = 0; i < 4; ++i) {
        int r = ty + i * 8;
        d[(size_t)(c0 + r) * R + r0 + tx] = (bf16)tile[tx][r];
    }
}

// ------------- tile scheduler (1 block) -------------
__global__ void sched_kernel(const int* __restrict__ counts, int* __restrict__ meta)
{
    if (threadIdx.x != 0) return;
    int* hdr = meta;
    int* s1 = meta + 2;            // 3*MT1 ints: e, row_base, list_idx
    int* s2 = meta + 2 + 3 * MT1;  // 3*MT2 ints
    int base = 0, t1 = 0, t2 = 0;
    for (int e = 0; e < NEXP; ++e) {
        int c = counts[e];
        int n1 = (c + 127) >> 7;
        for (int lt = 0; lt < n1; ++lt) {
            s1[t1 * 3] = e; s1[t1 * 3 + 1] = base + lt * 128; s1[t1 * 3 + 2] = lt * 128; ++t1;
        }
        int n2 = (c + 63) >> 6;
        for (int lt = 0; lt < n2; ++lt) {
            s2[t2 * 3] = e; s2[t2 * 3 + 1] = base + lt * 64; s2[t2 * 3 + 2] = lt * 64; ++t2;
        }
        base += n1 << 7;
    }
    hdr[0] = t1; hdr[1] = t2;
}

// ------------- layer1: h = relu(X_gather @ W1_e + b1), tile 128x128, K=512 -------------
__global__ __launch_bounds__(256, 2) void l1_kernel(
    const bf16* __restrict__ xb, const bf16* __restrict__ W1t,
    const float* __restrict__ b1, const int* __restrict__ counts,
    const int* __restrict__ tlist, const int* __restrict__ meta,
    bf16* __restrict__ h)
{
    int mt = blockIdx.x >> 3, nt = blockIdx.x & 7;
    if (mt >= meta[0]) return;
    const int* s1 = meta + 2 + mt * 3;
    int e = s1[0], rb = s1[1], i0 = s1[2];
    int cnt = counts[e];

    __shared__ __align__(16) char lds[32768];  // 2 bufs x (A 8KB + B 8KB)

    int tid = threadIdx.x, w = tid >> 6, l = tid & 63;
    int c0 = w * 128 + l, c1 = c0 + 64;
    int rA0 = c0 >> 2, kA0 = c0 & 3;
    int rA1 = c1 >> 2, kA1 = c1 & 3;
    int iA0 = i0 + rA0, iA1 = i0 + rA1;
    int tok0 = iA0 < cnt ? (tlist[e * N_TOK + iA0] >> 1) : 0;
    int tok1 = iA1 < cnt ? (tlist[e * N_TOK + iA1] >> 1) : 0;
    const bf16* sA0 = xb + (size_t)tok0 * DIM + kA0 * 8;
    const bf16* sA1 = xb + (size_t)tok1 * DIM + kA1 * 8;
    int n0 = nt * 128;
    const bf16* w1e = W1t + (size_t)e * HID * DIM;
    const bf16* sB0 = w1e + (size_t)(n0 + rA0) * DIM + kA0 * 8;
    const bf16* sB1 = w1e + (size_t)(n0 + rA1) * DIM + kA1 * 8;
    int oA0 = c0 * 16, oA1 = c1 * 16;

    f32x4 acc[4][4];
#pragma unroll
    for (int mf = 0; mf < 4; ++mf)
#pragma unroll
        for (int nf = 0; nf < 4; ++nf) acc[mf][nf] = (f32x4){0.f, 0.f, 0.f, 0.f};

    int wm = w >> 1, wn = w & 1;
    int lr = l & 15, kb = (l >> 4) * 16;

    {
        char* A = lds;       char* B = lds + 8192;
        gload16(sA0, A + oA0); gload16(sA1, A + oA1);
        gload16(sB0, B + oA0); gload16(sB1, B + oA1);
    }

    for (int ks = 0; ks < 16; ++ks) {
        __syncthreads();
        if (ks < 15) {
            char* A = lds + (((ks + 1) & 1) * 16384);
            char* B = A + 8192;
            int kof = (ks + 1) * 32;
            gload16(sA0 + kof, A + oA0); gload16(sA1 + kof, A + oA1);
            gload16(sB0 + kof, B + oA0); gload16(sB1 + kof, B + oA1);
        }
        char* A = lds + ((ks & 1) * 16384);
        char* B = A + 8192;
        bf16x8 af[4], bfr[4];
#pragma unroll
        for (int mf = 0; mf < 4; ++mf)
            af[mf] = *(const bf16x8*)(A + (wm * 64 + mf * 16 + lr) * 64 + kb);
#pragma unroll
        for (int nf = 0; nf < 4; ++nf)
            bfr[nf] = *(const bf16x8*)(B + (wn * 64 + nf * 16 + lr) * 64 + kb);
#pragma unroll
        for (int mf = 0; mf < 4; ++mf)
#pragma unroll
            for (int nf = 0; nf < 4; ++nf)
                acc[mf][nf] = mfma16(af[mf], bfr[nf], acc[mf][nf]);
    }

    const float* b1e = b1 + e * HID;
#pragma unroll
    for (int nf = 0; nf < 4; ++nf) {
        int colg = n0 + wn * 64 + nf * 16 + lr;
        float bias = b1e[colg];
#pragma unroll
        for (int mf = 0; mf < 4; ++mf) {
#pragma unroll
            for (int r = 0; r < 4; ++r) {
                int gr = rb + wm * 64 + mf * 16 + (l >> 4) * 4 + r;
                float v = fmaxf(acc[mf][nf][r] + bias, 0.f);
                h[(size_t)gr * HID + colg] = (bf16)v;
            }
        }
    }
}

// ------------- layer2: ybuf[pick] = h @ W2_e, tile 64x128, K=1024 -------------
__global__ __launch_bounds__(256, 2) void l2_kernel(
    const bf16* __restrict__ h, const bf16* __restrict__ W2t,
    const int* __restrict__ counts, const int* __restrict__ tlist,
    const int* __restrict__ meta, bf16* __restrict__ ybuf)
{
    int mt = blockIdx.x >> 2, nt = blockIdx.x & 3;
    if (mt >= meta[1]) return;
    const int* s2 = meta + 2 + 3 * MT1 + mt * 3;
    int e = s2[0], rb = s2[1], i0 = s2[2];
    int cnt = counts[e];

    __shared__ __align__(16) char lds[24576];

    int tid = threadIdx.x, w = tid >> 6, l = tid & 63;
    int cA = w * 64 + l;            int rA = cA >> 2, kA = cA & 3;
    int cB0 = w * 128 + l, cB1 = cB0 + 64;
    int rB0 = cB0 >> 2, kB0 = cB0 & 3;
    int rB1 = cB1 >> 2, kB1 = cB1 & 3;
    int n0 = nt * 128;
    const bf16* sA = h + (size_t)(rb + rA) * HID + kA * 8;
    const bf16* w2e = W2t + (size_t)e * OUTD * HID;
    const bf16* sB0 = w2e + (size_t)(n0 + rB0) * HID + kB0 * 8;
    const bf16* sB1 = w2e + (size_t)(n0 + rB1) * HID + kB1 * 8;
    int oA = cA * 16, oB0 = cB0 * 16, oB1 = cB1 * 16;

    f32x4 acc[2][4];
#pragma unroll
    for (int mf = 0; mf < 2; ++mf)
#pragma unroll
        for (int nf = 0; nf < 4; ++nf) acc[mf][nf] = (f32x4){0.f, 0.f, 0.f, 0.f};

    int wm = w >> 1, wn = w & 1;
    int lr = l & 15, kb = (l >> 4) * 16;

    {
        char* A = lds;       char* B = lds + 4096;
        gload16(sA, A + oA); gload16(sB0, B + oB0); gload16(sB1, B + oB1);
    }

    for (int ks = 0; ks < 32; ++ks) {
        __syncthreads();
        if (ks < 31) {
            char* A = lds + (((ks + 1) & 1) * 12288);
            char* B = A + 4096;
            int kof = (ks + 1) * 32;
            gload16(sA + kof, A + oA);
            gload16(sB0 + kof, B + oB0); gload16(sB1 + kof, B + oB1);
        }
        char* A = lds + ((ks & 1) * 12288);
        char* B = A + 4096;
        bf16x8 af[2], bfr[4];
#pragma unroll
        for (int mf = 0; mf < 2; ++mf)
            af[mf] = *(const bf16x8*)(A + (wm * 32 + mf * 16 + lr) * 64 + kb);
#pragma unroll
        for (int nf = 0; nf < 4; ++nf)
            bfr[nf] = *(const bf16x8*)(B + (wn * 64 + nf * 16 + lr) * 64 + kb);
#pragma unroll
        for (int mf = 0; mf < 2; ++mf)
#pragma unroll
            for (int nf = 0; nf < 4; ++nf)
                acc[mf][nf] = mfma16(af[mf], bfr[nf], acc[mf][nf]);
    }

    // epilogue: raw y -> ybuf[pick_index] (bf16), no bias/weight/atomics
#pragma unroll
    for (int mf = 0; mf < 2; ++mf) {
#pragma unroll
        for (int r = 0; r < 4; ++r) {
            int rloc = wm * 32 + mf * 16 + (l >> 4) * 4 + r;
            int i = i0 + rloc;
            if (i < cnt) {
                int pi = tlist[e * N_TOK + i];
                bf16* yrow = ybuf + (size_t)pi * OUTD;
#pragma unroll
                for (int nf = 0; nf < 4; ++nf) {
                    int colg = n0 + wn * 64 + nf * 16 + lr;
                    yrow[colg] = (bf16)acc[mf][nf][r];
                }
            }
        }
    }
}

// ------------- combine: out[n] = w0*(y0+b2[e0]) + w1*(y1+b2[e1]) -------------
__global__ __launch_bounds__(256) void combine_kernel(
    const bf16* __restrict__ ybuf, const float* __restrict__ b2,
    const int* __restrict__ pick_e, const float* __restrict__ pick_w,
    float* __restrict__ out)
{
    int wave = threadIdx.x >> 6;
    int lane = threadIdx.x & 63;
    int n = blockIdx.x * 4 + wave;

    int e0 = pick_e[n * 2], e1 = pick_e[n * 2 + 1];
    float w0 = pick_w[n * 2], w1 = pick_w[n * 2 + 1];

    const bf16x8* y0 = (const bf16x8*)(ybuf + (size_t)(n * 2) * OUTD);
    const bf16x8* y1 = (const bf16x8*)(ybuf + (size_t)(n * 2 + 1) * OUTD);
    const float4* b20 = (const float4*)(b2 + e0 * OUTD);
    const float4* b21 = (const float4*)(b2 + e1 * OUTD);
    float4* o4 = (float4*)(out + (size_t)n * OUTD);

    bf16x8 a = y0[lane];
    bf16x8 b = y1[lane];
    float4 c0 = b20[lane * 2], c1 = b20[lane * 2 + 1];
    float4 d0 = b21[lane * 2], d1 = b21[lane * 2 + 1];

    float4 r0, r1;
    r0.x = w0 * ((float)a[0] + c0.x) + w1 * ((float)b[0] + d0.x);
    r0.y = w0 * ((float)a[1] + c0.y) + w1 * ((float)b[1] + d0.y);
    r0.z = w0 * ((float)a[2] + c0.z) + w1 * ((float)b[2] + d0.z);
    r0.w = w0 * ((float)a[3] + c0.w) + w1 * ((float)b[3] + d0.w);
    r1.x = w0 * ((float)a[4] + c1.x) + w1 * ((float)b[4] + d1.x);
    r1.y = w0 * ((float)a[5] + c1.y) + w1 * ((float)b[5] + d1.y);
    r1.z = w0 * ((float)a[6] + c1.z) + w1 * ((float)b[6] + d1.z);
    r1.w = w0 * ((float)a[7] + c1.w) + w1 * ((float)b[7] + d1.w);
    o4[lane * 2]     = r0;
    o4[lane * 2 + 1] = r1;
}

extern "C" void kernel_launch(void* const* d_in, const int* in_sizes, int n_in,
                              void* d_out, int out_size, void* d_ws, size_t ws_size,
                              hipStream_t stream)
{
    const float* x  = (const float*)d_in[0];
    const float* W1 = (const float*)d_in[1];
    const float* b1 = (const float*)d_in[2];
    const float* W2 = (const float*)d_in[3];
    const float* b2 = (const float*)d_in[4];
    const float* Wg = (const float*)d_in[5];
    const float* bg = (const float*)d_in[6];

    float* out_f   = (float*)d_out;
    float* gates_o = out_f + (size_t)N_TOK * OUTD;
    float* topi_o  = gates_o + (size_t)N_TOK * NEXP;

    char* ws = (char*)d_ws;
    size_t offW1t  = 0;                                           // 8 MB
    size_t offW2t  = offW1t + (size_t)NEXP * HID * DIM * 2;       // 8 MB
    size_t offXb   = offW2t + (size_t)NEXP * OUTD * HID * 2;      // 4 MB
    size_t offH    = offXb + (size_t)N_TOK * DIM * 2;             // 18.9 MB
    size_t offYb   = offH + (size_t)HROWS * HID * 2;              // 8 MB
    size_t offCnt  = offYb + (size_t)N_TOK * 2 * OUTD * 2;
    size_t offTl   = offCnt + 256;
    size_t offMeta = offTl + (size_t)NEXP * N_TOK * 4;
    size_t offPkE  = offMeta + 4096;
    size_t offPkW  = offPkE + (size_t)N_TOK * 2 * 4;
    size_t offWgT  = offPkW + (size_t)N_TOK * 2 * 4;

    bf16*  W1t    = (bf16*)(ws + offW1t);
    bf16*  W2t    = (bf16*)(ws + offW2t);
    bf16*  xbuf   = (bf16*)(ws + offXb);
    bf16*  hbuf   = (bf16*)(ws + offH);
    bf16*  ybuf   = (bf16*)(ws + offYb);
    int*   cnts   = (int*)(ws + offCnt);
    int*   tlist  = (int*)(ws + offTl);
    int*   meta   = (int*)(ws + offMeta);
    int*   pick_e = (int*)(ws + offPkE);
    float* pick_w = (float*)(ws + offPkW);
    float* WgT    = (float*)(ws + offWgT);

    wgt_kernel<<<1, 256, 0, stream>>>(Wg, WgT);

    gate_kernel<<<N_TOK / 4, 256, 0, stream>>>(x, WgT, bg, xbuf, gates_o, topi_o,
                                               pick_e, pick_w);

    transpose_kernel<<<dim3(HID / 32, DIM / 32, NEXP), 256, 0, stream>>>(
        W1, W1t, DIM, HID);
    transpose_kernel<<<dim3(OUTD / 32, HID / 32, NEXP), 256, 0, stream>>>(
        W2, W2t, HID, OUTD);

    bucket_kernel<<<NEXP, 256, 0, stream>>>(pick_e, cnts, tlist);

    sched_kernel<<<1, 64, 0, stream>>>(cnts, meta);

    l1_kernel<<<MT1 * 8, 256, 0, stream>>>(xbuf, W1t, b1, cnts, tlist, meta, hbuf);
    l2_kernel<<<MT2 * 4, 256, 0, stream>>>(hbuf, W2t, cnts, tlist, meta, ybuf);

    combine_kernel<<<N_TOK / 4, 256, 0, stream>>>(ybuf, b2, pick_e, pick_w, out_f);
}

// Round 5
// 87.709 us; speedup vs baseline: 3.0723x; 1.1085x over previous
//
#include <hip/hip_runtime.h>
#include <hip/hip_bf16.h>

#define N_TOK 4096
#define DIM   512
#define HID   1024
#define OUTD  512
#define NEXP  8
#define TOPK  2

#define MT1 72     // max 128-row M-tiles
#define HROWS 9216 // max padded rows

typedef __bf16 bf16;
typedef bf16  bf16x8 __attribute__((ext_vector_type(8)));
typedef bf16  bf16x4 __attribute__((ext_vector_type(4)));
typedef float f32x4  __attribute__((ext_vector_type(4)));

__device__ inline f32x4 mfma16(bf16x8 a, bf16x8 b, f32x4 c) {
    return __builtin_amdgcn_mfma_f32_16x16x32_bf16(a, b, c, 0, 0, 0);
}

__device__ inline void gload16(const bf16* g, char* l) {
    __builtin_amdgcn_global_load_lds(
        (const __attribute__((address_space(1))) void*)g,
        (__attribute__((address_space(3))) void*)l, 16, 0, 0);
}

// ------------- prep: W1/W2 transpose+bf16 + WgT, one launch -------------
// blocks [0,4096): W1 [512][1024] -> W1t [1024][512]   (per expert 512 tiles)
// blocks [4096,8192): W2 [1024][512] -> W2t [512][1024]
// block 8192: Wg [512][8] -> WgT [8][512]
__global__ __launch_bounds__(256) void prep_kernel(
    const float* __restrict__ W1, const float* __restrict__ W2,
    const float* __restrict__ Wg,
    bf16* __restrict__ W1t, bf16* __restrict__ W2t, float* __restrict__ WgT)
{
    int b = blockIdx.x;
    if (b == 8192) {
        for (int i = threadIdx.x; i < DIM * NEXP; i += 256) {
            int d = i >> 3, e = i & 7;
            WgT[e * DIM + d] = Wg[i];
        }
        return;
    }
    const float* src; bf16* dst; int R, C, tilex, rem, e;
    if (b < 4096) {
        e = b >> 9; rem = b & 511; R = DIM; C = HID; tilex = 32;
        src = W1; dst = W1t;
    } else {
        b -= 4096;
        e = b >> 9; rem = b & 511; R = HID; C = OUTD; tilex = 16;
        src = W2; dst = W2t;
    }
    const float* s = src + (size_t)e * R * C;
    bf16* d = dst + (size_t)e * R * C;
    int c0 = (rem % tilex) * 32, r0 = (rem / tilex) * 32;

    __shared__ float tile[32][33];
    int tx = threadIdx.x & 31, ty = threadIdx.x >> 5;
#pragma unroll
    for (int i = 0; i < 4; ++i) {
        int r = ty + i * 8;
        tile[r][tx] = s[(size_t)(r0 + r) * C + c0 + tx];
    }
    __syncthreads();
#pragma unroll
    for (int i = 0; i < 4; ++i) {
        int r = ty + i * 8;
        d[(size_t)(c0 + r) * R + r0 + tx] = (bf16)tile[tx][r];
    }
}

// ------------- gating + x->bf16 convert -------------
__global__ __launch_bounds__(256) void gate_kernel(
    const float* __restrict__ x, const float* __restrict__ WgT,
    const float* __restrict__ bg, bf16* __restrict__ xb,
    float* __restrict__ gates_out, float* __restrict__ topi_out,
    int* __restrict__ pick_e, float* __restrict__ pick_w)
{
    int wave = threadIdx.x >> 6;
    int lane = threadIdx.x & 63;
    int n = blockIdx.x * 4 + wave;

    const float4* x4 = (const float4*)(x + (size_t)n * DIM);
    float4 v0 = x4[lane];
    float4 v1 = x4[lane + 64];

    bf16x4 o0 = { (bf16)v0.x, (bf16)v0.y, (bf16)v0.z, (bf16)v0.w };
    bf16x4 o1 = { (bf16)v1.x, (bf16)v1.y, (bf16)v1.z, (bf16)v1.w };
    bf16x4* xb4 = (bf16x4*)(xb + (size_t)n * DIM);
    xb4[lane]      = o0;
    xb4[lane + 64] = o1;

    float acc[NEXP];
#pragma unroll
    for (int e = 0; e < NEXP; ++e) {
        const float4* wr = (const float4*)(WgT + e * DIM);
        float4 w0 = wr[lane];
        float4 w1 = wr[lane + 64];
        acc[e] = v0.x * w0.x + v0.y * w0.y + v0.z * w0.z + v0.w * w0.w
               + v1.x * w1.x + v1.y * w1.y + v1.z * w1.z + v1.w * w1.w;
    }
#pragma unroll
    for (int off = 32; off >= 1; off >>= 1) {
#pragma unroll
        for (int e = 0; e < NEXP; ++e) acc[e] += __shfl_xor(acc[e], off, 64);
    }
#pragma unroll
    for (int e = 0; e < NEXP; ++e) acc[e] += bg[e];

    float m = acc[0];
#pragma unroll
    for (int e = 1; e < NEXP; ++e) m = fmaxf(m, acc[e]);
    float g[NEXP];
    float s = 0.f;
#pragma unroll
    for (int e = 0; e < NEXP; ++e) { g[e] = expf(acc[e] - m); s += g[e]; }
    float inv_s = 1.f / s;
#pragma unroll
    for (int e = 0; e < NEXP; ++e) g[e] *= inv_s;

    if (lane < NEXP) gates_out[n * NEXP + lane] = g[lane];

    if (lane == 0) {
        int m1 = 0;
#pragma unroll
        for (int e = 1; e < NEXP; ++e) if (g[e] > g[m1]) m1 = e;
        int m2 = (m1 == 0) ? 1 : 0;
#pragma unroll
        for (int e = 0; e < NEXP; ++e) if (e != m1 && g[e] > g[m2]) m2 = e;
        float v1g = g[m1], v2g = g[m2];
        float inv = 1.f / (v1g + v2g);
        topi_out[n * TOPK + 0] = (float)m1;
        topi_out[n * TOPK + 1] = (float)m2;
        int2 pe = { m1, m2 };
        float2 pw = { v1g * inv, v2g * inv };
        *(int2*)(pick_e + n * 2) = pe;
        *(float2*)(pick_w + n * 2) = pw;
    }
}

// ------------- bucket: 8 blocks (one per expert); stores pick-index -------------
__global__ __launch_bounds__(256) void bucket_kernel(
    const int* __restrict__ pick_e,
    int* __restrict__ counts, int* __restrict__ tlist)
{
    __shared__ int cnt;
    if (threadIdx.x == 0) cnt = 0;
    __syncthreads();
    int e = blockIdx.x;
    for (int i = threadIdx.x; i < N_TOK * 2; i += 256) {
        if (pick_e[i] == e) {
            int p = atomicAdd(&cnt, 1);
            tlist[e * N_TOK + p] = i;   // pick index: token*2 + slot
        }
    }
    __syncthreads();
    if (threadIdx.x == 0) counts[e] = cnt;
}

// ------------- tile scheduler (1 block): 128-row tiles shared by l1/l2 ----------
__global__ void sched_kernel(const int* __restrict__ counts, int* __restrict__ meta)
{
    if (threadIdx.x != 0) return;
    int* hdr = meta;
    int* s1 = meta + 2;            // 3*MT1 ints: e, row_base, list_idx
    int base = 0, t1 = 0;
    for (int e = 0; e < NEXP; ++e) {
        int c = counts[e];
        int n1 = (c + 127) >> 7;
        for (int lt = 0; lt < n1; ++lt) {
            s1[t1 * 3] = e; s1[t1 * 3 + 1] = base + lt * 128; s1[t1 * 3 + 2] = lt * 128; ++t1;
        }
        base += n1 << 7;
    }
    hdr[0] = t1;
}

// ------------- layer1: h = relu(X_gather @ W1_e + b1), tile 128x128, K=512 -------------
__global__ __launch_bounds__(256, 2) void l1_kernel(
    const bf16* __restrict__ xb, const bf16* __restrict__ W1t,
    const float* __restrict__ b1, const int* __restrict__ counts,
    const int* __restrict__ tlist, const int* __restrict__ meta,
    bf16* __restrict__ h)
{
    int mt = blockIdx.x >> 3, nt = blockIdx.x & 7;
    if (mt >= meta[0]) return;
    const int* s1 = meta + 2 + mt * 3;
    int e = s1[0], rb = s1[1], i0 = s1[2];
    int cnt = counts[e];

    __shared__ __align__(16) char lds[32768];  // 2 bufs x (A 8KB + B 8KB)

    int tid = threadIdx.x, w = tid >> 6, l = tid & 63;
    int c0 = w * 128 + l, c1 = c0 + 64;
    int rA0 = c0 >> 2, kA0 = c0 & 3;
    int rA1 = c1 >> 2, kA1 = c1 & 3;
    int iA0 = i0 + rA0, iA1 = i0 + rA1;
    int tok0 = iA0 < cnt ? (tlist[e * N_TOK + iA0] >> 1) : 0;
    int tok1 = iA1 < cnt ? (tlist[e * N_TOK + iA1] >> 1) : 0;
    const bf16* sA0 = xb + (size_t)tok0 * DIM + kA0 * 8;
    const bf16* sA1 = xb + (size_t)tok1 * DIM + kA1 * 8;
    int n0 = nt * 128;
    const bf16* w1e = W1t + (size_t)e * HID * DIM;
    const bf16* sB0 = w1e + (size_t)(n0 + rA0) * DIM + kA0 * 8;
    const bf16* sB1 = w1e + (size_t)(n0 + rA1) * DIM + kA1 * 8;
    int oA0 = c0 * 16, oA1 = c1 * 16;

    f32x4 acc[4][4];
#pragma unroll
    for (int mf = 0; mf < 4; ++mf)
#pragma unroll
        for (int nf = 0; nf < 4; ++nf) acc[mf][nf] = (f32x4){0.f, 0.f, 0.f, 0.f};

    int wm = w >> 1, wn = w & 1;
    int lr = l & 15, kb = (l >> 4) * 16;

    {
        char* A = lds;       char* B = lds + 8192;
        gload16(sA0, A + oA0); gload16(sA1, A + oA1);
        gload16(sB0, B + oA0); gload16(sB1, B + oA1);
    }

    for (int ks = 0; ks < 16; ++ks) {
        __syncthreads();
        if (ks < 15) {
            char* A = lds + (((ks + 1) & 1) * 16384);
            char* B = A + 8192;
            int kof = (ks + 1) * 32;
            gload16(sA0 + kof, A + oA0); gload16(sA1 + kof, A + oA1);
            gload16(sB0 + kof, B + oA0); gload16(sB1 + kof, B + oA1);
        }
        char* A = lds + ((ks & 1) * 16384);
        char* B = A + 8192;
        bf16x8 af[4], bfr[4];
#pragma unroll
        for (int mf = 0; mf < 4; ++mf)
            af[mf] = *(const bf16x8*)(A + (wm * 64 + mf * 16 + lr) * 64 + kb);
#pragma unroll
        for (int nf = 0; nf < 4; ++nf)
            bfr[nf] = *(const bf16x8*)(B + (wn * 64 + nf * 16 + lr) * 64 + kb);
#pragma unroll
        for (int mf = 0; mf < 4; ++mf)
#pragma unroll
            for (int nf = 0; nf < 4; ++nf)
                acc[mf][nf] = mfma16(af[mf], bfr[nf], acc[mf][nf]);
    }

    const float* b1e = b1 + e * HID;
#pragma unroll
    for (int nf = 0; nf < 4; ++nf) {
        int colg = n0 + wn * 64 + nf * 16 + lr;
        float bias = b1e[colg];
#pragma unroll
        for (int mf = 0; mf < 4; ++mf) {
#pragma unroll
            for (int r = 0; r < 4; ++r) {
                int gr = rb + wm * 64 + mf * 16 + (l >> 4) * 4 + r;
                float v = fmaxf(acc[mf][nf][r] + bias, 0.f);
                h[(size_t)gr * HID + colg] = (bf16)v;
            }
        }
    }
}

// ------------- layer2: ybuf[pick] = h @ W2_e, tile 128x128, K=1024 -------------
__global__ __launch_bounds__(256, 2) void l2_kernel(
    const bf16* __restrict__ h, const bf16* __restrict__ W2t,
    const int* __restrict__ counts, const int* __restrict__ tlist,
    const int* __restrict__ meta, bf16* __restrict__ ybuf)
{
    int mt = blockIdx.x >> 2, nt = blockIdx.x & 3;
    if (mt >= meta[0]) return;
    const int* s1 = meta + 2 + mt * 3;
    int e = s1[0], rb = s1[1], i0 = s1[2];
    int cnt = counts[e];

    __shared__ __align__(16) char lds[32768];  // 2 bufs x (A 8KB + B 8KB)

    int tid = threadIdx.x, w = tid >> 6, l = tid & 63;
    int c0 = w * 128 + l, c1 = c0 + 64;
    int rA0 = c0 >> 2, kA0 = c0 & 3;
    int rA1 = c1 >> 2, kA1 = c1 & 3;
    const bf16* sA0 = h + (size_t)(rb + rA0) * HID + kA0 * 8;
    const bf16* sA1 = h + (size_t)(rb + rA1) * HID + kA1 * 8;
    int n0 = nt * 128;
    const bf16* w2e = W2t + (size_t)e * OUTD * HID;
    const bf16* sB0 = w2e + (size_t)(n0 + rA0) * HID + kA0 * 8;
    const bf16* sB1 = w2e + (size_t)(n0 + rA1) * HID + kA1 * 8;
    int oA0 = c0 * 16, oA1 = c1 * 16;

    f32x4 acc[4][4];
#pragma unroll
    for (int mf = 0; mf < 4; ++mf)
#pragma unroll
        for (int nf = 0; nf < 4; ++nf) acc[mf][nf] = (f32x4){0.f, 0.f, 0.f, 0.f};

    int wm = w >> 1, wn = w & 1;
    int lr = l & 15, kb = (l >> 4) * 16;

    {
        char* A = lds;       char* B = lds + 8192;
        gload16(sA0, A + oA0); gload16(sA1, A + oA1);
        gload16(sB0, B + oA0); gload16(sB1, B + oA1);
    }

    for (int ks = 0; ks < 32; ++ks) {
        __syncthreads();
        if (ks < 31) {
            char* A = lds + (((ks + 1) & 1) * 16384);
            char* B = A + 8192;
            int kof = (ks + 1) * 32;
            gload16(sA0 + kof, A + oA0); gload16(sA1 + kof, A + oA1);
            gload16(sB0 + kof, B + oA0); gload16(sB1 + kof, B + oA1);
        }
        char* A = lds + ((ks & 1) * 16384);
        char* B = A + 8192;
        bf16x8 af[4], bfr[4];
#pragma unroll
        for (int mf = 0; mf < 4; ++mf)
            af[mf] = *(const bf16x8*)(A + (wm * 64 + mf * 16 + lr) * 64 + kb);
#pragma unroll
        for (int nf = 0; nf < 4; ++nf)
            bfr[nf] = *(const bf16x8*)(B + (wn * 64 + nf * 16 + lr) * 64 + kb);
#pragma unroll
        for (int mf = 0; mf < 4; ++mf)
#pragma unroll
            for (int nf = 0; nf < 4; ++nf)
                acc[mf][nf] = mfma16(af[mf], bfr[nf], acc[mf][nf]);
    }

    // epilogue: raw y -> ybuf[pick_index] (bf16); padding rows discarded
#pragma unroll
    for (int mf = 0; mf < 4; ++mf) {
#pragma unroll
        for (int r = 0; r < 4; ++r) {
            int rloc = wm * 64 + mf * 16 + (l >> 4) * 4 + r;
            int i = i0 + rloc;
            if (i < cnt) {
                int pi = tlist[e * N_TOK + i];
                bf16* yrow = ybuf + (size_t)pi * OUTD;
#pragma unroll
                for (int nf = 0; nf < 4; ++nf) {
                    int colg = n0 + wn * 64 + nf * 16 + lr;
                    yrow[colg] = (bf16)acc[mf][nf][r];
                }
            }
        }
    }
}

// ------------- combine: out[n] = w0*(y0+b2[e0]) + w1*(y1+b2[e1]) -------------
__global__ __launch_bounds__(256) void combine_kernel(
    const bf16* __restrict__ ybuf, const float* __restrict__ b2,
    const int* __restrict__ pick_e, const float* __restrict__ pick_w,
    float* __restrict__ out)
{
    int wave = threadIdx.x >> 6;
    int lane = threadIdx.x & 63;
    int n = blockIdx.x * 4 + wave;

    int e0 = pick_e[n * 2], e1 = pick_e[n * 2 + 1];
    float w0 = pick_w[n * 2], w1 = pick_w[n * 2 + 1];

    const bf16x8* y0 = (const bf16x8*)(ybuf + (size_t)(n * 2) * OUTD);
    const bf16x8* y1 = (const bf16x8*)(ybuf + (size_t)(n * 2 + 1) * OUTD);
    const float4* b20 = (const float4*)(b2 + e0 * OUTD);
    const float4* b21 = (const float4*)(b2 + e1 * OUTD);
    float4* o4 = (float4*)(out + (size_t)n * OUTD);

    bf16x8 a = y0[lane];
    bf16x8 b = y1[lane];
    float4 c0 = b20[lane * 2], c1 = b20[lane * 2 + 1];
    float4 d0 = b21[lane * 2], d1 = b21[lane * 2 + 1];

    float4 r0, r1;
    r0.x = w0 * ((float)a[0] + c0.x) + w1 * ((float)b[0] + d0.x);
    r0.y = w0 * ((float)a[1] + c0.y) + w1 * ((float)b[1] + d0.y);
    r0.z = w0 * ((float)a[2] + c0.z) + w1 * ((float)b[2] + d0.z);
    r0.w = w0 * ((float)a[3] + c0.w) + w1 * ((float)b[3] + d0.w);
    r1.x = w0 * ((float)a[4] + c1.x) + w1 * ((float)b[4] + d1.x);
    r1.y = w0 * ((float)a[5] + c1.y) + w1 * ((float)b[5] + d1.y);
    r1.z = w0 * ((float)a[6] + c1.z) + w1 * ((float)b[6] + d1.z);
    r1.w = w0 * ((float)a[7] + c1.w) + w1 * ((float)b[7] + d1.w);
    o4[lane * 2]     = r0;
    o4[lane * 2 + 1] = r1;
}

extern "C" void kernel_launch(void* const* d_in, const int* in_sizes, int n_in,
                              void* d_out, int out_size, void* d_ws, size_t ws_size,
                              hipStream_t stream)
{
    const float* x  = (const float*)d_in[0];
    const float* W1 = (const float*)d_in[1];
    const float* b1 = (const float*)d_in[2];
    const float* W2 = (const float*)d_in[3];
    const float* b2 = (const float*)d_in[4];
    const float* Wg = (const float*)d_in[5];
    const float* bg = (const float*)d_in[6];

    float* out_f   = (float*)d_out;
    float* gates_o = out_f + (size_t)N_TOK * OUTD;
    float* topi_o  = gates_o + (size_t)N_TOK * NEXP;

    char* ws = (char*)d_ws;
    size_t offW1t  = 0;                                           // 8 MB
    size_t offW2t  = offW1t + (size_t)NEXP * HID * DIM * 2;       // 8 MB
    size_t offXb   = offW2t + (size_t)NEXP * OUTD * HID * 2;      // 4 MB
    size_t offH    = offXb + (size_t)N_TOK * DIM * 2;             // 18.9 MB
    size_t offYb   = offH + (size_t)HROWS * HID * 2;              // 8 MB
    size_t offCnt  = offYb + (size_t)N_TOK * 2 * OUTD * 2;
    size_t offTl   = offCnt + 256;
    size_t offMeta = offTl + (size_t)NEXP * N_TOK * 4;
    size_t offPkE  = offMeta + 4096;
    size_t offPkW  = offPkE + (size_t)N_TOK * 2 * 4;
    size_t offWgT  = offPkW + (size_t)N_TOK * 2 * 4;

    bf16*  W1t    = (bf16*)(ws + offW1t);
    bf16*  W2t    = (bf16*)(ws + offW2t);
    bf16*  xbuf   = (bf16*)(ws + offXb);
    bf16*  hbuf   = (bf16*)(ws + offH);
    bf16*  ybuf   = (bf16*)(ws + offYb);
    int*   cnts   = (int*)(ws + offCnt);
    int*   tlist  = (int*)(ws + offTl);
    int*   meta   = (int*)(ws + offMeta);
    int*   pick_e = (int*)(ws + offPkE);
    float* pick_w = (float*)(ws + offPkW);
    float* WgT    = (float*)(ws + offWgT);

    prep_kernel<<<8193, 256, 0, stream>>>(W1, W2, Wg, W1t, W2t, WgT);

    gate_kernel<<<N_TOK / 4, 256, 0, stream>>>(x, WgT, bg, xbuf, gates_o, topi_o,
                                               pick_e, pick_w);

    bucket_kernel<<<NEXP, 256, 0, stream>>>(pick_e, cnts, tlist);

    sched_kernel<<<1, 64, 0, stream>>>(cnts, meta);

    l1_kernel<<<MT1 * 8, 256, 0, stream>>>(xbuf, W1t, b1, cnts, tlist, meta, hbuf);
    l2_kernel<<<MT1 * 4, 256, 0, stream>>>(hbuf, W2t, cnts, tlist, meta, ybuf);

    combine_kernel<<<N_TOK / 4, 256, 0, stream>>>(ybuf, b2, pick_e, pick_w, out_f);
}

// Round 6
// 76.941 us; speedup vs baseline: 3.5023x; 1.1400x over previous
//
#include <hip/hip_runtime.h>
#include <hip/hip_bf16.h>

#define N_TOK 4096
#define DIM   512
#define HID   1024
#define OUTD  512
#define NEXP  8
#define TOPK  2

#define MT1 72     // max 128-row M-tiles
#define HROWS 9216 // max padded rows

typedef __bf16 bf16;
typedef bf16  bf16x8 __attribute__((ext_vector_type(8)));
typedef bf16  bf16x4 __attribute__((ext_vector_type(4)));
typedef float f32x4  __attribute__((ext_vector_type(4)));

__device__ inline f32x4 mfma16(bf16x8 a, bf16x8 b, f32x4 c) {
    return __builtin_amdgcn_mfma_f32_16x16x32_bf16(a, b, c, 0, 0, 0);
}

__device__ inline void gload16(const bf16* g, char* l) {
    __builtin_amdgcn_global_load_lds(
        (const __attribute__((address_space(1))) void*)g,
        (__attribute__((address_space(3))) void*)l, 16, 0, 0);
}

// ------------- prep (W1/W2 transpose->bf16) + gate, one launch -------------
// blocks [0,4096): W1 [512][1024] -> W1t [1024][512]
// blocks [4096,8192): W2 [1024][512] -> W2t [512][1024]
// blocks [8192,9216): gating (4 tokens per block); WgT built in LDS
__global__ __launch_bounds__(256) void prep_gate_kernel(
    const float* __restrict__ W1, const float* __restrict__ W2,
    const float* __restrict__ Wg, const float* __restrict__ bg,
    const float* __restrict__ x,
    bf16* __restrict__ W1t, bf16* __restrict__ W2t,
    bf16* __restrict__ xb,
    float* __restrict__ gates_out, float* __restrict__ topi_out,
    int* __restrict__ pick_e, float* __restrict__ pick_w)
{
    __shared__ __align__(16) float smem[NEXP * DIM];   // 16 KB (gate) / tile (prep)
    int b = blockIdx.x;

    if (b >= 8192) {
        // ---------------- gate path ----------------
        // build WgT[e][d] in LDS
        const float4* Wg4 = (const float4*)Wg;
        for (int i = threadIdx.x; i < DIM * NEXP / 4; i += 256) {
            float4 v = Wg4[i];
#pragma unroll
            for (int j = 0; j < 4; ++j) {
                int idx = i * 4 + j;
                smem[(idx & 7) * DIM + (idx >> 3)] = ((const float*)&v)[j];
            }
        }
        __syncthreads();

        int wave = threadIdx.x >> 6;
        int lane = threadIdx.x & 63;
        int n = (b - 8192) * 4 + wave;

        const float4* x4 = (const float4*)(x + (size_t)n * DIM);
        float4 v0 = x4[lane];
        float4 v1 = x4[lane + 64];

        bf16x4 o0 = { (bf16)v0.x, (bf16)v0.y, (bf16)v0.z, (bf16)v0.w };
        bf16x4 o1 = { (bf16)v1.x, (bf16)v1.y, (bf16)v1.z, (bf16)v1.w };
        bf16x4* xb4 = (bf16x4*)(xb + (size_t)n * DIM);
        xb4[lane]      = o0;
        xb4[lane + 64] = o1;

        float acc[NEXP];
#pragma unroll
        for (int e = 0; e < NEXP; ++e) {
            const float4* wr = (const float4*)(smem + e * DIM);
            float4 w0 = wr[lane];
            float4 w1 = wr[lane + 64];
            acc[e] = v0.x * w0.x + v0.y * w0.y + v0.z * w0.z + v0.w * w0.w
                   + v1.x * w1.x + v1.y * w1.y + v1.z * w1.z + v1.w * w1.w;
        }
#pragma unroll
        for (int off = 32; off >= 1; off >>= 1) {
#pragma unroll
            for (int e = 0; e < NEXP; ++e) acc[e] += __shfl_xor(acc[e], off, 64);
        }
#pragma unroll
        for (int e = 0; e < NEXP; ++e) acc[e] += bg[e];

        float m = acc[0];
#pragma unroll
        for (int e = 1; e < NEXP; ++e) m = fmaxf(m, acc[e]);
        float g[NEXP];
        float s = 0.f;
#pragma unroll
        for (int e = 0; e < NEXP; ++e) { g[e] = expf(acc[e] - m); s += g[e]; }
        float inv_s = 1.f / s;
#pragma unroll
        for (int e = 0; e < NEXP; ++e) g[e] *= inv_s;

        if (lane < NEXP) gates_out[n * NEXP + lane] = g[lane];

        if (lane == 0) {
            int m1 = 0;
#pragma unroll
            for (int e = 1; e < NEXP; ++e) if (g[e] > g[m1]) m1 = e;
            int m2 = (m1 == 0) ? 1 : 0;
#pragma unroll
            for (int e = 0; e < NEXP; ++e) if (e != m1 && g[e] > g[m2]) m2 = e;
            float v1g = g[m1], v2g = g[m2];
            float inv = 1.f / (v1g + v2g);
            topi_out[n * TOPK + 0] = (float)m1;
            topi_out[n * TOPK + 1] = (float)m2;
            int2 pe = { m1, m2 };
            float2 pw = { v1g * inv, v2g * inv };
            *(int2*)(pick_e + n * 2) = pe;
            *(float2*)(pick_w + n * 2) = pw;
        }
        return;
    }

    // ---------------- transpose path ----------------
    float (*tile)[33] = (float(*)[33])smem;   // [32][33]
    const float* src; bf16* dst; int R, C, tilex, rem, e;
    if (b < 4096) {
        e = b >> 9; rem = b & 511; R = DIM; C = HID; tilex = 32;
        src = W1; dst = W1t;
    } else {
        b -= 4096;
        e = b >> 9; rem = b & 511; R = HID; C = OUTD; tilex = 16;
        src = W2; dst = W2t;
    }
    const float* s = src + (size_t)e * R * C;
    bf16* d = dst + (size_t)e * R * C;
    int c0 = (rem % tilex) * 32, r0 = (rem / tilex) * 32;

    int tx = threadIdx.x & 31, ty = threadIdx.x >> 5;
#pragma unroll
    for (int i = 0; i < 4; ++i) {
        int r = ty + i * 8;
        tile[r][tx] = s[(size_t)(r0 + r) * C + c0 + tx];
    }
    __syncthreads();

    // coalesced bf16x4 stores: thread t -> dst row c0+(t>>3), cols r0+(t&7)*4..+3
    int t = threadIdx.x;
    int dc = t >> 3, q = t & 7;
    bf16x4 v;
#pragma unroll
    for (int j = 0; j < 4; ++j) v[j] = (bf16)tile[q * 4 + j][dc];
    *(bf16x4*)(d + (size_t)(c0 + dc) * R + r0 + q * 4) = v;
}

// ------------- bucket + tile scheduler: one block, 1024 threads -------------
__global__ __launch_bounds__(1024) void bucket_sched_kernel(
    const int* __restrict__ pick_e,
    int* __restrict__ counts, int* __restrict__ tlist, int* __restrict__ meta)
{
    __shared__ int cnt[NEXP];
    if (threadIdx.x < NEXP) cnt[threadIdx.x] = 0;
    __syncthreads();
    for (int i = threadIdx.x; i < N_TOK * 2; i += 1024) {
        int e = pick_e[i];
        int p = atomicAdd(&cnt[e], 1);
        tlist[e * N_TOK + p] = i;   // pick index: token*2 + slot
    }
    __syncthreads();
    if (threadIdx.x == 0) {
        int base = 0, t1 = 0;
        for (int e = 0; e < NEXP; ++e) {
            int c = cnt[e];
            counts[e] = c;
            int n1 = (c + 127) >> 7;
            for (int lt = 0; lt < n1; ++lt) {
                meta[2 + t1 * 3]     = e;
                meta[2 + t1 * 3 + 1] = base + lt * 128;
                meta[2 + t1 * 3 + 2] = lt * 128;
                ++t1;
            }
            base += n1 << 7;
        }
        meta[0] = t1;
    }
}

// Swizzled K-inner LDS layout (rule #21: linear LDS dest for global_load_lds,
// inverse-swizzled global SOURCE, same swizzle on the ds_read):
//   slot(row,kc) = row*4 + (kc ^ h(row)),  h(row) = (row&3) ^ ((row>>2)&1)
// -> fragment-read groups hit each bank-quad exactly twice (2-way = free),
//    and each row's 4 source chunks still cover its contiguous 64B.

// ------------- layer1: h = relu(X_gather @ W1_e + b1), tile 128x128, K=512 -------------
__global__ __launch_bounds__(256, 4) void l1_kernel(
    const bf16* __restrict__ xb, const bf16* __restrict__ W1t,
    const float* __restrict__ b1, const int* __restrict__ counts,
    const int* __restrict__ tlist, const int* __restrict__ meta,
    bf16* __restrict__ h)
{
    int mt = blockIdx.x >> 3, nt = blockIdx.x & 7;
    if (mt >= meta[0]) return;
    const int* s1 = meta + 2 + mt * 3;
    int e = s1[0], rb = s1[1], i0 = s1[2];
    int cnt = counts[e];

    __shared__ __align__(16) char lds[32768];  // 2 bufs x (A 8KB + B 8KB)

    int tid = threadIdx.x, w = tid >> 6, l = tid & 63;
    int c0 = w * 128 + l, c1 = c0 + 64;
    int rA0 = c0 >> 2, rA1 = c1 >> 2;
    int kA0 = (c0 & 3) ^ ((rA0 & 3) ^ ((rA0 >> 2) & 1));
    int kA1 = (c1 & 3) ^ ((rA1 & 3) ^ ((rA1 >> 2) & 1));
    int iA0 = i0 + rA0, iA1 = i0 + rA1;
    int tok0 = iA0 < cnt ? (tlist[e * N_TOK + iA0] >> 1) : 0;
    int tok1 = iA1 < cnt ? (tlist[e * N_TOK + iA1] >> 1) : 0;
    const bf16* sA0 = xb + (size_t)tok0 * DIM + kA0 * 8;
    const bf16* sA1 = xb + (size_t)tok1 * DIM + kA1 * 8;
    int n0 = nt * 128;
    const bf16* w1e = W1t + (size_t)e * HID * DIM;
    const bf16* sB0 = w1e + (size_t)(n0 + rA0) * DIM + kA0 * 8;
    const bf16* sB1 = w1e + (size_t)(n0 + rA1) * DIM + kA1 * 8;
    int oA0 = c0 * 16, oA1 = c1 * 16;

    f32x4 acc[4][4];
#pragma unroll
    for (int mf = 0; mf < 4; ++mf)
#pragma unroll
        for (int nf = 0; nf < 4; ++nf) acc[mf][nf] = (f32x4){0.f, 0.f, 0.f, 0.f};

    int wm = w >> 1, wn = w & 1;
    int lr = l & 15;
    int kb = (((l >> 4) ^ ((l & 3) ^ ((l >> 2) & 1)))) * 16;  // swizzled k-chunk

    {
        char* A = lds;       char* B = lds + 8192;
        gload16(sA0, A + oA0); gload16(sA1, A + oA1);
        gload16(sB0, B + oA0); gload16(sB1, B + oA1);
    }

    for (int ks = 0; ks < 16; ++ks) {
        __syncthreads();
        if (ks < 15) {
            char* A = lds + (((ks + 1) & 1) * 16384);
            char* B = A + 8192;
            int kof = (ks + 1) * 32;
            gload16(sA0 + kof, A + oA0); gload16(sA1 + kof, A + oA1);
            gload16(sB0 + kof, B + oA0); gload16(sB1 + kof, B + oA1);
        }
        char* A = lds + ((ks & 1) * 16384);
        char* B = A + 8192;
        bf16x8 af[4], bfr[4];
#pragma unroll
        for (int mf = 0; mf < 4; ++mf)
            af[mf] = *(const bf16x8*)(A + (wm * 64 + mf * 16 + lr) * 64 + kb);
#pragma unroll
        for (int nf = 0; nf < 4; ++nf)
            bfr[nf] = *(const bf16x8*)(B + (wn * 64 + nf * 16 + lr) * 64 + kb);
#pragma unroll
        for (int mf = 0; mf < 4; ++mf)
#pragma unroll
            for (int nf = 0; nf < 4; ++nf)
                acc[mf][nf] = mfma16(af[mf], bfr[nf], acc[mf][nf]);
    }

    const float* b1e = b1 + e * HID;
#pragma unroll
    for (int nf = 0; nf < 4; ++nf) {
        int colg = n0 + wn * 64 + nf * 16 + lr;
        float bias = b1e[colg];
#pragma unroll
        for (int mf = 0; mf < 4; ++mf) {
#pragma unroll
            for (int r = 0; r < 4; ++r) {
                int gr = rb + wm * 64 + mf * 16 + (l >> 4) * 4 + r;
                float v = fmaxf(acc[mf][nf][r] + bias, 0.f);
                h[(size_t)gr * HID + colg] = (bf16)v;
            }
        }
    }
}

// ------------- layer2: ybuf[pick] = h @ W2_e, tile 128x128, K=1024 -------------
__global__ __launch_bounds__(256, 4) void l2_kernel(
    const bf16* __restrict__ h, const bf16* __restrict__ W2t,
    const int* __restrict__ counts, const int* __restrict__ tlist,
    const int* __restrict__ meta, bf16* __restrict__ ybuf)
{
    int mt = blockIdx.x >> 2, nt = blockIdx.x & 3;
    if (mt >= meta[0]) return;
    const int* s1 = meta + 2 + mt * 3;
    int e = s1[0], rb = s1[1], i0 = s1[2];
    int cnt = counts[e];

    __shared__ __align__(16) char lds[32768];

    int tid = threadIdx.x, w = tid >> 6, l = tid & 63;
    int c0 = w * 128 + l, c1 = c0 + 64;
    int rA0 = c0 >> 2, rA1 = c1 >> 2;
    int kA0 = (c0 & 3) ^ ((rA0 & 3) ^ ((rA0 >> 2) & 1));
    int kA1 = (c1 & 3) ^ ((rA1 & 3) ^ ((rA1 >> 2) & 1));
    const bf16* sA0 = h + (size_t)(rb + rA0) * HID + kA0 * 8;
    const bf16* sA1 = h + (size_t)(rb + rA1) * HID + kA1 * 8;
    int n0 = nt * 128;
    const bf16* w2e = W2t + (size_t)e * OUTD * HID;
    const bf16* sB0 = w2e + (size_t)(n0 + rA0) * HID + kA0 * 8;
    const bf16* sB1 = w2e + (size_t)(n0 + rA1) * HID + kA1 * 8;
    int oA0 = c0 * 16, oA1 = c1 * 16;

    f32x4 acc[4][4];
#pragma unroll
    for (int mf = 0; mf < 4; ++mf)
#pragma unroll
        for (int nf = 0; nf < 4; ++nf) acc[mf][nf] = (f32x4){0.f, 0.f, 0.f, 0.f};

    int wm = w >> 1, wn = w & 1;
    int lr = l & 15;
    int kb = (((l >> 4) ^ ((l & 3) ^ ((l >> 2) & 1)))) * 16;

    {
        char* A = lds;       char* B = lds + 8192;
        gload16(sA0, A + oA0); gload16(sA1, A + oA1);
        gload16(sB0, B + oA0); gload16(sB1, B + oA1);
    }

    for (int ks = 0; ks < 32; ++ks) {
        __syncthreads();
        if (ks < 31) {
            char* A = lds + (((ks + 1) & 1) * 16384);
            char* B = A + 8192;
            int kof = (ks + 1) * 32;
            gload16(sA0 + kof, A + oA0); gload16(sA1 + kof, A + oA1);
            gload16(sB0 + kof, B + oA0); gload16(sB1 + kof, B + oA1);
        }
        char* A = lds + ((ks & 1) * 16384);
        char* B = A + 8192;
        bf16x8 af[4], bfr[4];
#pragma unroll
        for (int mf = 0; mf < 4; ++mf)
            af[mf] = *(const bf16x8*)(A + (wm * 64 + mf * 16 + lr) * 64 + kb);
#pragma unroll
        for (int nf = 0; nf < 4; ++nf)
            bfr[nf] = *(const bf16x8*)(B + (wn * 64 + nf * 16 + lr) * 64 + kb);
#pragma unroll
        for (int mf = 0; mf < 4; ++mf)
#pragma unroll
            for (int nf = 0; nf < 4; ++nf)
                acc[mf][nf] = mfma16(af[mf], bfr[nf], acc[mf][nf]);
    }

    // epilogue: raw y -> ybuf[pick_index] (bf16); padding rows discarded
#pragma unroll
    for (int mf = 0; mf < 4; ++mf) {
#pragma unroll
        for (int r = 0; r < 4; ++r) {
            int rloc = wm * 64 + mf * 16 + (l >> 4) * 4 + r;
            int i = i0 + rloc;
            if (i < cnt) {
                int pi = tlist[e * N_TOK + i];
                bf16* yrow = ybuf + (size_t)pi * OUTD;
#pragma unroll
                for (int nf = 0; nf < 4; ++nf) {
                    int colg = n0 + wn * 64 + nf * 16 + lr;
                    yrow[colg] = (bf16)acc[mf][nf][r];
                }
            }
        }
    }
}

// ------------- combine: out[n] = w0*(y0+b2[e0]) + w1*(y1+b2[e1]) -------------
__global__ __launch_bounds__(256) void combine_kernel(
    const bf16* __restrict__ ybuf, const float* __restrict__ b2,
    const int* __restrict__ pick_e, const float* __restrict__ pick_w,
    float* __restrict__ out)
{
    int wave = threadIdx.x >> 6;
    int lane = threadIdx.x & 63;
    int n = blockIdx.x * 4 + wave;

    int e0 = pick_e[n * 2], e1 = pick_e[n * 2 + 1];
    float w0 = pick_w[n * 2], w1 = pick_w[n * 2 + 1];

    const bf16x8* y0 = (const bf16x8*)(ybuf + (size_t)(n * 2) * OUTD);
    const bf16x8* y1 = (const bf16x8*)(ybuf + (size_t)(n * 2 + 1) * OUTD);
    const float4* b20 = (const float4*)(b2 + e0 * OUTD);
    const float4* b21 = (const float4*)(b2 + e1 * OUTD);
    float4* o4 = (float4*)(out + (size_t)n * OUTD);

    bf16x8 a = y0[lane];
    bf16x8 b = y1[lane];
    float4 c0 = b20[lane * 2], c1 = b20[lane * 2 + 1];
    float4 d0 = b21[lane * 2], d1 = b21[lane * 2 + 1];

    float4 r0, r1;
    r0.x = w0 * ((float)a[0] + c0.x) + w1 * ((float)b[0] + d0.x);
    r0.y = w0 * ((float)a[1] + c0.y) + w1 * ((float)b[1] + d0.y);
    r0.z = w0 * ((float)a[2] + c0.z) + w1 * ((float)b[2] + d0.z);
    r0.w = w0 * ((float)a[3] + c0.w) + w1 * ((float)b[3] + d0.w);
    r1.x = w0 * ((float)a[4] + c1.x) + w1 * ((float)b[4] + d1.x);
    r1.y = w0 * ((float)a[5] + c1.y) + w1 * ((float)b[5] + d1.y);
    r1.z = w0 * ((float)a[6] + c1.z) + w1 * ((float)b[6] + d1.z);
    r1.w = w0 * ((float)a[7] + c1.w) + w1 * ((float)b[7] + d1.w);
    o4[lane * 2]     = r0;
    o4[lane * 2 + 1] = r1;
}

extern "C" void kernel_launch(void* const* d_in, const int* in_sizes, int n_in,
                              void* d_out, int out_size, void* d_ws, size_t ws_size,
                              hipStream_t stream)
{
    const float* x  = (const float*)d_in[0];
    const float* W1 = (const float*)d_in[1];
    const float* b1 = (const float*)d_in[2];
    const float* W2 = (const float*)d_in[3];
    const float* b2 = (const float*)d_in[4];
    const float* Wg = (const float*)d_in[5];
    const float* bg = (const float*)d_in[6];

    float* out_f   = (float*)d_out;
    float* gates_o = out_f + (size_t)N_TOK * OUTD;
    float* topi_o  = gates_o + (size_t)N_TOK * NEXP;

    char* ws = (char*)d_ws;
    size_t offW1t  = 0;                                           // 8 MB
    size_t offW2t  = offW1t + (size_t)NEXP * HID * DIM * 2;       // 8 MB
    size_t offXb   = offW2t + (size_t)NEXP * OUTD * HID * 2;      // 4 MB
    size_t offH    = offXb + (size_t)N_TOK * DIM * 2;             // 18.9 MB
    size_t offYb   = offH + (size_t)HROWS * HID * 2;              // 8 MB
    size_t offCnt  = offYb + (size_t)N_TOK * 2 * OUTD * 2;
    size_t offTl   = offCnt + 256;
    size_t offMeta = offTl + (size_t)NEXP * N_TOK * 4;
    size_t offPkE  = offMeta + 4096;
    size_t offPkW  = offPkE + (size_t)N_TOK * 2 * 4;

    bf16*  W1t    = (bf16*)(ws + offW1t);
    bf16*  W2t    = (bf16*)(ws + offW2t);
    bf16*  xbuf   = (bf16*)(ws + offXb);
    bf16*  hbuf   = (bf16*)(ws + offH);
    bf16*  ybuf   = (bf16*)(ws + offYb);
    int*   cnts   = (int*)(ws + offCnt);
    int*   tlist  = (int*)(ws + offTl);
    int*   meta   = (int*)(ws + offMeta);
    int*   pick_e = (int*)(ws + offPkE);
    float* pick_w = (float*)(ws + offPkW);

    prep_gate_kernel<<<8192 + N_TOK / 4, 256, 0, stream>>>(
        W1, W2, Wg, bg, x, W1t, W2t, xbuf, gates_o, topi_o, pick_e, pick_w);

    bucket_sched_kernel<<<1, 1024, 0, stream>>>(pick_e, cnts, tlist, meta);

    l1_kernel<<<MT1 * 8, 256, 0, stream>>>(xbuf, W1t, b1, cnts, tlist, meta, hbuf);
    l2_kernel<<<MT1 * 4, 256, 0, stream>>>(hbuf, W2t, cnts, tlist, meta, ybuf);

    combine_kernel<<<N_TOK / 4, 256, 0, stream>>>(ybuf, b2, pick_e, pick_w, out_f);
}